// Round 4
// baseline (912.897 us; speedup 1.0000x reference)
//
#include <hip/hip_runtime.h>

// Problem constants
#define CDIM   192
#define NHEADS 6
#define KDIM   32
#define NTOK   49          // tokens per window (7x7)
#define NPIX   3136        // 56*56
#define NB     32
#define NWIN   2048        // 32 * 8 * 8
#define CHUNKW 512         // windows per chunk
#define NCHUNK 4
#define CHUNKM (CHUNKW*NTOK)   // 25088
#define QKVN   576
#define HIDDEN 768
#define LN_EPS 1e-5f
#define BN_EPS 1e-5f
#define WSTR   28224       // 3*6*49*32 bf16 elements per window in qkv scratch
#define NTOKALL 100352     // 32*3136
#define LUTN   513         // gelu gate LUT: [-8,8] step 1/32

typedef __attribute__((ext_vector_type(8))) short bf16x8;   // 8 bf16 = 4 VGPRs
typedef __attribute__((ext_vector_type(4))) float f32x4;

__device__ __forceinline__ unsigned short f2bf(float f) {
    unsigned u = __float_as_uint(f);
    return (unsigned short)((u + 0x7FFFu + ((u >> 16) & 1u)) >> 16);   // RNE
}
__device__ __forceinline__ float bf2f(unsigned short s) {
    return __uint_as_float(((unsigned)s) << 16);
}

// ------------------------------------------- weight swizzle: fp32 KxN -> bf16 frags
// frag layout: subtile id = (n0/16)*(K/32) + (k0/32); lane L holds
// W[k0 + (L>>4)*8 + j][n0 + (L&15)], j=0..7, stored as 16B per lane.
__global__ void kw_swz(const float* __restrict__ W, unsigned short* __restrict__ o,
                       int K, int N) {
    int t = blockIdx.x * 256 + threadIdx.x;
    int lane = t & 63, sub = t >> 6;
    int ksub = K >> 5;
    int total = (N >> 4) * ksub;
    if (sub >= total) return;
    int nfr = sub / ksub, kk = sub - nfr * ksub;
    int n = nfr * 16 + (lane & 15);
    int kb = kk * 32 + (lane >> 4) * 8;
    unsigned p0 = (unsigned)f2bf(W[(size_t)(kb + 0) * N + n]) |
                  ((unsigned)f2bf(W[(size_t)(kb + 1) * N + n]) << 16);
    unsigned p1 = (unsigned)f2bf(W[(size_t)(kb + 2) * N + n]) |
                  ((unsigned)f2bf(W[(size_t)(kb + 3) * N + n]) << 16);
    unsigned p2 = (unsigned)f2bf(W[(size_t)(kb + 4) * N + n]) |
                  ((unsigned)f2bf(W[(size_t)(kb + 5) * N + n]) << 16);
    unsigned p3 = (unsigned)f2bf(W[(size_t)(kb + 6) * N + n]) |
                  ((unsigned)f2bf(W[(size_t)(kb + 7) * N + n]) << 16);
    uint4 v = {p0, p1, p2, p3};
    *(uint4*)(o + (size_t)(sub * 64 + lane) * 8) = v;
}

// --------- conv/BN prep + gelu-gate LUT: cw [C][9] -> cwT [9][C]; BN fold; LUT
__global__ void k_prep_conv(const float* __restrict__ cw,
    const float* __restrict__ bg, const float* __restrict__ bb,
    const float* __restrict__ bm, const float* __restrict__ bv,
    float* __restrict__ cwT, float* __restrict__ bnsc, float* __restrict__ bnbi,
    float* __restrict__ lutG)
{
    int t = threadIdx.x + blockIdx.x * 256;
    if (t < 9 * CDIM) {
        int tap = t / CDIM, c = t - tap * CDIM;
        cwT[t] = cw[c * 9 + tap];
    }
    if (t < CDIM) {
        float s = bg[t] * rsqrtf(bv[t] + BN_EPS);
        bnsc[t] = s;
        bnbi[t] = bb[t] - bm[t] * s;
    }
    if (t < LUTN) {
        float xv = -8.0f + (float)t * (1.0f / 32.0f);
        lutG[t] = 0.5f * (1.0f + erff(xv * 0.70710678118654752f));
    }
}

// ---------------------------------------------------------------- k0: LN1 stats
__global__ void k0_stats(const float* __restrict__ x, float* __restrict__ mv) {
    int t    = blockIdx.x * 4 + (threadIdx.x >> 6);
    int lane = threadIdx.x & 63;
    const float* row = x + (size_t)t * CDIM;
    float e0 = row[lane], e1 = row[lane + 64], e2 = row[lane + 128];
    float s = e0 + e1 + e2;
    for (int o = 32; o; o >>= 1) s += __shfl_xor(s, o);
    float m = s * (1.0f / 192.0f);
    float d0 = e0 - m, d1 = e1 - m, d2 = e2 - m;
    float v = d0*d0 + d1*d1 + d2*d2;
    for (int o = 32; o; o >>= 1) v += __shfl_xor(v, o);
    if (lane == 0) {
        mv[t] = m;
        mv[NTOKALL + t] = 1.0f / sqrtf(v * (1.0f / 192.0f) + LN_EPS);
    }
}

// ------------------------------------------------- k1: LN1 + QKV GEMM (MFMA bf16)
__global__ __launch_bounds__(256) void k1_qkv_mfma(
    const float* __restrict__ x,  const float* __restrict__ mv,
    const float* __restrict__ g1, const float* __restrict__ b1,
    const unsigned short* __restrict__ wsw, const float* __restrict__ qb,
    unsigned short* __restrict__ qkv, int wbase)
{
    const int tid = threadIdx.x;
    const int w = tid >> 6, L = tid & 63, quad = L >> 4, l15 = L & 15;
    const int m0 = blockIdx.x * 64;
    const int Nt = blockIdx.y;                 // 0..2
    int mA = m0 + w * 16 + l15;
    int gt = wbase * NTOK + mA;
    int wg = gt / 49, tok = gt - wg * 49;
    int bb = wg >> 6, wrem = wg & 63;
    int rr = tok / 7, cc = tok - rr * 7;
    int xrow = bb * NPIX + ((wrem >> 3) * 7 + rr) * 56 + (wrem & 7) * 7 + cc;
    float mean = mv[xrow], rstd = mv[NTOKALL + xrow];
    const float* xr = x + (size_t)xrow * CDIM;
    bf16x8 a[6];
#pragma unroll
    for (int kk = 0; kk < 6; ++kk) {
        int c0 = kk * 32 + quad * 8;
        float4 xv0 = *(const float4*)&xr[c0], xv1 = *(const float4*)&xr[c0 + 4];
        float4 gv0 = *(const float4*)&g1[c0], gv1 = *(const float4*)&g1[c0 + 4];
        float4 bv0 = *(const float4*)&b1[c0], bv1 = *(const float4*)&b1[c0 + 4];
        bf16x8 av;
        av[0] = (short)f2bf((xv0.x - mean) * rstd * gv0.x + bv0.x);
        av[1] = (short)f2bf((xv0.y - mean) * rstd * gv0.y + bv0.y);
        av[2] = (short)f2bf((xv0.z - mean) * rstd * gv0.z + bv0.z);
        av[3] = (short)f2bf((xv0.w - mean) * rstd * gv0.w + bv0.w);
        av[4] = (short)f2bf((xv1.x - mean) * rstd * gv1.x + bv1.x);
        av[5] = (short)f2bf((xv1.y - mean) * rstd * gv1.y + bv1.y);
        av[6] = (short)f2bf((xv1.z - mean) * rstd * gv1.z + bv1.z);
        av[7] = (short)f2bf((xv1.w - mean) * rstd * gv1.w + bv1.w);
        a[kk] = av;
    }
    f32x4 acc[12];
#pragma unroll
    for (int nf = 0; nf < 12; ++nf) acc[nf] = (f32x4){0.f, 0.f, 0.f, 0.f};
    const bf16x8* B = (const bf16x8*)wsw;
#pragma unroll
    for (int kk = 0; kk < 6; ++kk) {
#pragma unroll
        for (int nf = 0; nf < 12; ++nf) {
            bf16x8 bfr = B[(size_t)((Nt * 12 + nf) * 6 + kk) * 64 + L];
            acc[nf] = __builtin_amdgcn_mfma_f32_16x16x32_bf16(a[kk], bfr, acc[nf], 0, 0, 0);
        }
    }
    float qbv[12];
#pragma unroll
    for (int nf = 0; nf < 12; ++nf) qbv[nf] = qb[Nt * 192 + nf * 16 + l15];
#pragma unroll
    for (int i = 0; i < 4; ++i) {
        int mrow = m0 + w * 16 + quad * 4 + i;
        int wrel = mrow / 49, tokr = mrow - wrel * 49;
        unsigned short* obase = qkv + (size_t)wrel * WSTR + tokr * 32;
#pragma unroll
        for (int nf = 0; nf < 12; ++nf) {
            int n = Nt * 192 + nf * 16 + l15;
            int h = n / 96, rem = n - h * 96;
            int part = rem >> 5, d = rem & 31;
            obase[(size_t)(part * 6 + h) * 1568 + d] = f2bf(acc[nf][i] + qbv[nf]);
        }
    }
}

// ----------------------------------------------- k2: windowed attention (head pair)
__global__ __launch_bounds__(128) void k2_attn(
    unsigned short* __restrict__ qkv, const float* __restrict__ abias)
{
    __shared__ float kv[6272];   // [kv part(2)][h(2)][tok 49][d 32], f32
    const int wrel = blockIdx.x / 3;
    const int pair = blockIdx.x - wrel * 3;
    const int h0 = pair * 2;
    unsigned short* base = qkv + (size_t)wrel * WSTR;
    for (int idx = threadIdx.x; idx < 784; idx += 128) {   // 8 elems each
        int part = idx / 392;
        int rem  = idx - part * 392;
        int h    = rem / 196;
        int off8 = rem - h * 196;
        bf16x8 v = *(const bf16x8*)&base[(size_t)((part + 1) * 6 + h0 + h) * 1568 + off8 * 8];
        float* dst = &kv[((part * 2 + h) * 196 + off8) * 8];
        float4 f0 = {bf2f((unsigned short)v[0]), bf2f((unsigned short)v[1]),
                     bf2f((unsigned short)v[2]), bf2f((unsigned short)v[3])};
        float4 f1 = {bf2f((unsigned short)v[4]), bf2f((unsigned short)v[5]),
                     bf2f((unsigned short)v[6]), bf2f((unsigned short)v[7])};
        *(float4*)&dst[0] = f0;
        *(float4*)&dst[4] = f1;
    }
    __syncthreads();
    const int item = threadIdx.x;
    if (item >= 98) return;
    const int h = item / 49;
    const int row = item - h * 49;
    const int hg = h0 + h;
    unsigned short* qptr = base + (size_t)hg * 1568 + row * 32;
    float4 q4[8];
#pragma unroll
    for (int dq2 = 0; dq2 < 4; ++dq2) {
        bf16x8 v = *(const bf16x8*)&qptr[dq2 * 8];
        q4[dq2 * 2]     = (float4){bf2f((unsigned short)v[0]), bf2f((unsigned short)v[1]),
                                   bf2f((unsigned short)v[2]), bf2f((unsigned short)v[3])};
        q4[dq2 * 2 + 1] = (float4){bf2f((unsigned short)v[4]), bf2f((unsigned short)v[5]),
                                   bf2f((unsigned short)v[6]), bf2f((unsigned short)v[7])};
    }
    const int rr = row / 7, rc = row - rr * 7;
    const float scale = 0.17677669529663687f;   // 32^-0.5
    const float* kbase = &kv[(h * 49) * 32];
    const float* vbase = &kv[(98 + h * 49) * 32];
    float s[49];
    for (int j = 0; j < 49; ++j) {
        const float* kr = kbase + j * 32;
        float4 a = {0, 0, 0, 0};
#pragma unroll
        for (int dq = 0; dq < 8; ++dq) {
            float4 k4 = *(const float4*)&kr[dq * 4];
            a.x += q4[dq].x * k4.x; a.y += q4[dq].y * k4.y;
            a.z += q4[dq].z * k4.z; a.w += q4[dq].w * k4.w;
        }
        int jr = j / 7, jc = j - jr * 7;
        int dy = rr > jr ? rr - jr : jr - rr;
        int dx = rc > jc ? rc - jc : jc - rc;
        s[j] = (a.x + a.y + a.z + a.w) * scale + abias[hg * 49 + dy * 7 + dx];
    }
    float mx = s[0];
    for (int j = 1; j < 49; ++j) mx = fmaxf(mx, s[j]);
    float sum = 0.0f;
    for (int j = 0; j < 49; ++j) { s[j] = __expf(s[j] - mx); sum += s[j]; }
    float rinv = 1.0f / sum;
    float4 o[8] = {};
    for (int j = 0; j < 49; ++j) {
        float p = s[j];
        const float* vr = vbase + j * 32;
#pragma unroll
        for (int dq = 0; dq < 8; ++dq) {
            float4 v4 = *(const float4*)&vr[dq * 4];
            o[dq].x += p * v4.x; o[dq].y += p * v4.y;
            o[dq].z += p * v4.z; o[dq].w += p * v4.w;
        }
    }
#pragma unroll
    for (int dq = 0; dq < 8; ++dq) {
        uint2 pk;
        pk.x = (unsigned)f2bf(o[dq].x * rinv) | ((unsigned)f2bf(o[dq].y * rinv) << 16);
        pk.y = (unsigned)f2bf(o[dq].z * rinv) | ((unsigned)f2bf(o[dq].w * rinv) << 16);
        *(uint2*)&qptr[dq * 4] = pk;       // overwrite q slot (own row only)
    }
}

// --------------------------- k3: proj GEMM (MFMA) + bias + residual + window reverse
__global__ __launch_bounds__(256) void k3_proj_mfma(
    const unsigned short* __restrict__ qkv, const float* __restrict__ x,
    const unsigned short* __restrict__ wsw, const float* __restrict__ pb,
    float* __restrict__ x1, int wbase)
{
    const int tid = threadIdx.x;
    const int w = tid >> 6, L = tid & 63, quad = L >> 4, l15 = L & 15;
    const int m0 = blockIdx.x * 64;
    const int Nt = blockIdx.y;                 // 0..2, 64 cols each
    int mA = m0 + w * 16 + l15;
    int wrelA = mA / 49, tokA = mA - wrelA * 49;
    const unsigned short* ar = qkv + (size_t)wrelA * WSTR + tokA * 32 + quad * 8;
    bf16x8 a[6];
#pragma unroll
    for (int kk = 0; kk < 6; ++kk)             // head = kk
        a[kk] = *(const bf16x8*)&ar[(size_t)kk * 1568];
    f32x4 acc[4];
#pragma unroll
    for (int nf = 0; nf < 4; ++nf) acc[nf] = (f32x4){0.f, 0.f, 0.f, 0.f};
    const bf16x8* B = (const bf16x8*)wsw;
#pragma unroll
    for (int kk = 0; kk < 6; ++kk) {
#pragma unroll
        for (int nf = 0; nf < 4; ++nf) {
            bf16x8 bfr = B[(size_t)((Nt * 4 + nf) * 6 + kk) * 64 + L];
            acc[nf] = __builtin_amdgcn_mfma_f32_16x16x32_bf16(a[kk], bfr, acc[nf], 0, 0, 0);
        }
    }
    float pbv[4];
#pragma unroll
    for (int nf = 0; nf < 4; ++nf) pbv[nf] = pb[Nt * 64 + nf * 16 + l15];
#pragma unroll
    for (int i = 0; i < 4; ++i) {
        int mrow = m0 + w * 16 + quad * 4 + i;
        int wrel = mrow / 49, tokr = mrow - wrel * 49;
        int wg = wbase + wrel;
        int bb = wg >> 6, wrem = wg & 63;
        int r = tokr / 7, c = tokr - r * 7;
        size_t xoff = ((size_t)(bb * NPIX + ((wrem >> 3) * 7 + r) * 56 + (wrem & 7) * 7 + c)) * CDIM;
#pragma unroll
        for (int nf = 0; nf < 4; ++nf) {
            int col = Nt * 64 + nf * 16 + l15;
            x1[xoff + col] = acc[nf][i] + pbv[nf] + x[xoff + col];
        }
    }
}

// ---------------------- k4: depthwise conv3x3 + BN + LN2 stats (1 wave per token)
// All loads are lane-coalesced float4 (cwT is [tap][C], BN prefolded) -- the
// R2 profile showed the [C][9] scattered cw loads cost ~1600 L1 lines/wave.
__global__ __launch_bounds__(256) void k4_convln(
    const float* __restrict__ x1, const float* __restrict__ cwT,
    const float* __restrict__ bnsc, const float* __restrict__ bnbi,
    float* __restrict__ x2, float* __restrict__ mv)
{
    const int w = threadIdx.x >> 6, lane = threadIdx.x & 63;
    const int t = blockIdx.x * 4 + w;
    const int b = t / NPIX, l = t - b * NPIX;
    const int yy = l / 56, xx = l - yy * 56;
    const bool act = lane < 48;
    const int c0 = lane * 4;
    float4 o = {0, 0, 0, 0};
    if (act) {
        const float* xb = x1 + (size_t)b * NPIX * CDIM;
        float4 acc = {0, 0, 0, 0};
#pragma unroll
        for (int dy = -1; dy <= 1; ++dy) {
            int y2 = yy + dy;
            if ((unsigned)y2 >= 56u) continue;
#pragma unroll
            for (int dx = -1; dx <= 1; ++dx) {
                int x2c = xx + dx;
                if ((unsigned)x2c >= 56u) continue;
                float4 v = *(const float4*)&xb[(size_t)(y2 * 56 + x2c) * CDIM + c0];
                int tap = (dy + 1) * 3 + (dx + 1);
                float4 wt = *(const float4*)&cwT[tap * CDIM + c0];
                acc.x += v.x * wt.x;
                acc.y += v.y * wt.y;
                acc.z += v.z * wt.z;
                acc.w += v.w * wt.w;
            }
        }
        float4 sc = *(const float4*)&bnsc[c0];
        float4 bi = *(const float4*)&bnbi[c0];
        o.x = acc.x * sc.x + bi.x;
        o.y = acc.y * sc.y + bi.y;
        o.z = acc.z * sc.z + bi.z;
        o.w = acc.w * sc.w + bi.w;
        *(float4*)&x2[(size_t)t * CDIM + c0] = o;
    }
    // LN2 stats (two-pass, butterfly gives sum to all lanes)
    float s = o.x + o.y + o.z + o.w;
    for (int off = 32; off; off >>= 1) s += __shfl_xor(s, off);
    float m = s * (1.0f / 192.0f);
    float d0 = o.x - m, d1 = o.y - m, d2 = o.z - m, d3 = o.w - m;
    float v2 = act ? (d0*d0 + d1*d1 + d2*d2 + d3*d3) : 0.0f;
    for (int off = 32; off; off >>= 1) v2 += __shfl_xor(v2, off);
    if (lane == 0) {
        mv[t] = m;
        mv[NTOKALL + t] = 1.0f / sqrtf(v2 * (1.0f / 192.0f) + LN_EPS);
    }
}

// --------------- k5: LN2 + FC1 + GELU + FC2 + residual (MFMA, LDS-staged A-frags)
// FC2 nf-split across waves (R2). GELU via LDS gate-LUT (513 nodes, [-8,8],
// linear interp, err ~3e-5 << bf16 quant): ~11 full-rate VALU + 1 ds_read2
// vs ~80 branchy instrs in ocml erff (R3 profile: 57% VALUBusy = 20K instr/thd).
__global__ __launch_bounds__(256) void k5_mlp_mfma(
    const float* __restrict__ x2, const float* __restrict__ mv2,
    const float* __restrict__ g2, const float* __restrict__ b2,
    const unsigned short* __restrict__ w1sw, const float* __restrict__ fb1,
    const unsigned short* __restrict__ w2sw, const float* __restrict__ fb2,
    const float* __restrict__ lutG, float* __restrict__ out)
{
    __shared__ unsigned short aFrag[24 * 512];   // [mf 4][kk 6][lane 64][8 bf16] = 24KB
    __shared__ unsigned short hsw[16 * 512];     // hidden chunk 64x128, A-frag layout
    __shared__ float lutg[520];                  // gelu gate LUT
    const int tid = threadIdx.x;
    const int w = tid >> 6, L = tid & 63, quad = L >> 4, l15 = L & 15;
    const int m0 = blockIdx.x * 64;
    for (int i = tid; i < LUTN; i += 256) lutg[i] = lutG[i];
    // ---- build LN2(x2) A-fragments into LDS (cooperative, 6 slots/thread)
#pragma unroll
    for (int rsl = 0; rsl < 6; ++rsl) {
        int s = tid + 256 * rsl;                 // 0..1535
        int mf = s / 384, rem = s - mf * 384;
        int kk = rem >> 6, La = rem & 63;
        int row = m0 + mf * 16 + (La & 15);
        int c0 = kk * 32 + (La >> 4) * 8;
        float mm = mv2[row], rs = mv2[NTOKALL + row];
        const float* xr = x2 + (size_t)row * CDIM + c0;
        float4 xv0 = *(const float4*)&xr[0], xv1 = *(const float4*)&xr[4];
        float4 gv0 = *(const float4*)&g2[c0], gv1 = *(const float4*)&g2[c0 + 4];
        float4 bv0 = *(const float4*)&b2[c0], bv1 = *(const float4*)&b2[c0 + 4];
        bf16x8 av;
        av[0] = (short)f2bf((xv0.x - mm) * rs * gv0.x + bv0.x);
        av[1] = (short)f2bf((xv0.y - mm) * rs * gv0.y + bv0.y);
        av[2] = (short)f2bf((xv0.z - mm) * rs * gv0.z + bv0.z);
        av[3] = (short)f2bf((xv0.w - mm) * rs * gv0.w + bv0.w);
        av[4] = (short)f2bf((xv1.x - mm) * rs * gv1.x + bv1.x);
        av[5] = (short)f2bf((xv1.y - mm) * rs * gv1.y + bv1.y);
        av[6] = (short)f2bf((xv1.z - mm) * rs * gv1.z + bv1.z);
        av[7] = (short)f2bf((xv1.w - mm) * rs * gv1.w + bv1.w);
        *(bf16x8*)&aFrag[(size_t)s * 8] = av;
    }
    __syncthreads();

    f32x4 acc2[4][3];    // [mf][nf]  cols = w*48 + nf*16 + l15
#pragma unroll
    for (int mf = 0; mf < 4; ++mf)
#pragma unroll
        for (int nf = 0; nf < 3; ++nf) acc2[mf][nf] = (f32x4){0.f, 0.f, 0.f, 0.f};
    const bf16x8* B1 = (const bf16x8*)w1sw;
    const bf16x8* B2 = (const bf16x8*)w2sw;

    for (int ch = 0; ch < 6; ++ch) {
        // ---- FC1: hidden cols [ch*128 + 32w, +32) for all 64 rows
        f32x4 acc1[4][2];
#pragma unroll
        for (int mf = 0; mf < 4; ++mf)
#pragma unroll
            for (int nf = 0; nf < 2; ++nf) acc1[mf][nf] = (f32x4){0.f, 0.f, 0.f, 0.f};
#pragma unroll
        for (int kk = 0; kk < 6; ++kk) {
            bf16x8 bfr0 = B1[(size_t)((ch * 8 + 2 * w + 0) * 6 + kk) * 64 + L];
            bf16x8 bfr1 = B1[(size_t)((ch * 8 + 2 * w + 1) * 6 + kk) * 64 + L];
#pragma unroll
            for (int mf = 0; mf < 4; ++mf) {
                bf16x8 av = *(const bf16x8*)&aFrag[(size_t)((mf * 6 + kk) * 64 + L) * 8];
                acc1[mf][0] = __builtin_amdgcn_mfma_f32_16x16x32_bf16(av, bfr0, acc1[mf][0], 0, 0, 0);
                acc1[mf][1] = __builtin_amdgcn_mfma_f32_16x16x32_bf16(av, bfr1, acc1[mf][1], 0, 0, 0);
            }
        }
        __syncthreads();   // prior FC2 reads of hsw complete
        // ---- GELU (LUT) + store hidden in A-frag layout (k-subtile = w)
#pragma unroll
        for (int mf = 0; mf < 4; ++mf) {
#pragma unroll
            for (int nf = 0; nf < 2; ++nf) {
                float bias = fb1[ch * 128 + 32 * w + nf * 16 + l15];
                int hi16 = (((nf * 16 + l15) >> 3) & 3) << 4;
#pragma unroll
                for (int i = 0; i < 4; ++i) {
                    float xg = acc1[mf][nf][i] + bias;
                    float p = fmaf(xg, 32.0f, 256.0f);            // (x+8)*32
                    p = fminf(fmaxf(p, 0.0f), 511.999f);
                    float fi = floorf(p);
                    int ii = (int)fi;
                    float fr = p - fi;
                    float g0 = lutg[ii], g1v = lutg[ii + 1];
                    float h = xg * fmaf(fr, g1v - g0, g0);
                    int Ls = (quad * 4 + i) | hi16;
                    hsw[(w * 4 + mf) * 512 + Ls * 8 + (L & 7)] = f2bf(h);
                }
            }
        }
        __syncthreads();
        // ---- FC2 partial (nf-split): acc2[mf][nf] over this chunk's 128 k
#pragma unroll
        for (int kk2 = 0; kk2 < 4; ++kk2) {
            bf16x8 a2[4];
#pragma unroll
            for (int mf = 0; mf < 4; ++mf)
                a2[mf] = *(const bf16x8*)&hsw[(size_t)((kk2 * 4 + mf) * 512) + (size_t)L * 8];
#pragma unroll
            for (int nf = 0; nf < 3; ++nf) {
                bf16x8 bfr = B2[(size_t)((w * 3 + nf) * 24 + ch * 4 + kk2) * 64 + L];
#pragma unroll
                for (int mf = 0; mf < 4; ++mf)
                    acc2[mf][nf] = __builtin_amdgcn_mfma_f32_16x16x32_bf16(a2[mf], bfr, acc2[mf][nf], 0, 0, 0);
            }
        }
    }
    // ---- epilogue: + fc2_b + residual(x2); wave w covers cols [48w, 48w+48)
    float fb2v[3];
#pragma unroll
    for (int nf = 0; nf < 3; ++nf) fb2v[nf] = fb2[w * 48 + nf * 16 + l15];
#pragma unroll
    for (int mf = 0; mf < 4; ++mf) {
#pragma unroll
        for (int i = 0; i < 4; ++i) {
            int row = m0 + mf * 16 + quad * 4 + i;
            const float* xr = x2 + (size_t)row * CDIM;
            float* orow = out + (size_t)row * CDIM;
#pragma unroll
            for (int nf = 0; nf < 3; ++nf) {
                int col = w * 48 + nf * 16 + l15;
                orow[col] = acc2[mf][nf][i] + fb2v[nf] + xr[col];
            }
        }
    }
}

// ------------------------------------------------------------------- launcher
extern "C" void kernel_launch(void* const* d_in, const int* in_sizes, int n_in,
                              void* d_out, int out_size, void* d_ws, size_t ws_size,
                              hipStream_t stream) {
    const float* x     = (const float*)d_in[0];
    const float* g1    = (const float*)d_in[1];
    const float* b1    = (const float*)d_in[2];
    const float* qkvw  = (const float*)d_in[3];
    const float* qkvb  = (const float*)d_in[4];
    const float* abias = (const float*)d_in[5];
    const float* projw = (const float*)d_in[6];
    const float* projb = (const float*)d_in[7];
    const float* convw = (const float*)d_in[8];
    const float* bng   = (const float*)d_in[9];
    const float* bnb   = (const float*)d_in[10];
    const float* bnm   = (const float*)d_in[11];
    const float* bnv   = (const float*)d_in[12];
    const float* g2    = (const float*)d_in[13];
    const float* b2    = (const float*)d_in[14];
    const float* fc1w  = (const float*)d_in[15];
    const float* fc1b  = (const float*)d_in[16];
    const float* fc2w  = (const float*)d_in[17];
    const float* fc2b  = (const float*)d_in[18];
    float* out = (float*)d_out;

    // ws layout (floats):
    //   [0, 19267584)            qkv bf16 chunk scratch (28.9MB used) / later x2 fp32 (77MB)
    //   [19267584, 19468288)     LN mean/rstd (LN1, then overwritten by LN2 stats in k4)
    //   [19468288, 19689472)     swizzled bf16 weights (884,736 B)
    //   [19689472, ...)          cwT (1728) + bnsc (192) + bnbi (192) + lutG (513)
    float* wsf   = (float*)d_ws;
    unsigned short* qkvws = (unsigned short*)wsf;
    float* x2b   = wsf;
    float* mv    = wsf + 19267584;
    unsigned short* qkvw_sw = (unsigned short*)(wsf + 19468288);
    unsigned short* projw_sw = qkvw_sw + 110592;
    unsigned short* fc1_sw   = projw_sw + 36864;
    unsigned short* fc2_sw   = fc1_sw + 147456;
    float* cwT  = wsf + 19689472;
    float* bnsc = cwT + 1728;
    float* bnbi = bnsc + 192;
    float* lutG = bnbi + 192;

    kw_swz<<<(216 * 64 + 255) / 256, 256, 0, stream>>>(qkvw, qkvw_sw, CDIM, QKVN);
    kw_swz<<<(72  * 64 + 255) / 256, 256, 0, stream>>>(projw, projw_sw, CDIM, CDIM);
    kw_swz<<<(288 * 64 + 255) / 256, 256, 0, stream>>>(fc1w, fc1_sw, CDIM, HIDDEN);
    kw_swz<<<(288 * 64 + 255) / 256, 256, 0, stream>>>(fc2w, fc2_sw, HIDDEN, CDIM);
    k_prep_conv<<<7, 256, 0, stream>>>(convw, bng, bnb, bnm, bnv, cwT, bnsc, bnbi, lutG);

    k0_stats<<<NTOKALL / 4, 256, 0, stream>>>(x, mv);
    for (int chunk = 0; chunk < NCHUNK; ++chunk) {
        int wbase = chunk * CHUNKW;
        k1_qkv_mfma<<<dim3(CHUNKM / 64, 3), 256, 0, stream>>>(
            x, mv, g1, b1, qkvw_sw, qkvb, qkvws, wbase);
        k2_attn<<<CHUNKW * 3, 128, 0, stream>>>(qkvws, abias);
        k3_proj_mfma<<<dim3(CHUNKM / 64, 3), 256, 0, stream>>>(
            qkvws, x, projw_sw, projb, out, wbase);
    }
    k4_convln<<<NTOKALL / 4, 256, 0, stream>>>(out, cwT, bnsc, bnbi, x2b, mv);
    k5_mlp_mfma<<<NTOKALL / 64, 256, 0, stream>>>(
        x2b, mv, g2, b2, fc1_sw, fc1b, fc2_sw, fc2b, lutG, out);
}

// Round 5
// 865.069 us; speedup vs baseline: 1.0553x; 1.0553x over previous
//
#include <hip/hip_runtime.h>

// Problem constants
#define CDIM   192
#define NHEADS 6
#define KDIM   32
#define NTOK   49          // tokens per window (7x7)
#define NPIX   3136        // 56*56
#define NB     32
#define NWIN   2048        // 32 * 8 * 8
#define CHUNKW 512         // windows per chunk
#define NCHUNK 4
#define CHUNKM (CHUNKW*NTOK)   // 25088
#define QKVN   576
#define HIDDEN 768
#define LN_EPS 1e-5f
#define BN_EPS 1e-5f
#define WSTR   28224       // 3*6*49*32 bf16 elements per window in qkv scratch
#define NTOKALL 100352     // 32*3136

typedef __attribute__((ext_vector_type(8))) short bf16x8;   // 8 bf16 = 4 VGPRs
typedef __attribute__((ext_vector_type(4))) float f32x4;

__device__ __forceinline__ unsigned short f2bf(float f) {
    unsigned u = __float_as_uint(f);
    return (unsigned short)((u + 0x7FFFu + ((u >> 16) & 1u)) >> 16);   // RNE
}
__device__ __forceinline__ float bf2f(unsigned short s) {
    return __uint_as_float(((unsigned)s) << 16);
}

// ------------------------------------------- weight swizzle: fp32 KxN -> bf16 frags
// frag layout: subtile id = (n0/16)*(K/32) + (k0/32); lane L holds
// W[k0 + (L>>4)*8 + j][n0 + (L&15)], j=0..7, stored as 16B per lane.
__global__ void kw_swz(const float* __restrict__ W, unsigned short* __restrict__ o,
                       int K, int N) {
    int t = blockIdx.x * 256 + threadIdx.x;
    int lane = t & 63, sub = t >> 6;
    int ksub = K >> 5;
    int total = (N >> 4) * ksub;
    if (sub >= total) return;
    int nfr = sub / ksub, kk = sub - nfr * ksub;
    int n = nfr * 16 + (lane & 15);
    int kb = kk * 32 + (lane >> 4) * 8;
    unsigned p0 = (unsigned)f2bf(W[(size_t)(kb + 0) * N + n]) |
                  ((unsigned)f2bf(W[(size_t)(kb + 1) * N + n]) << 16);
    unsigned p1 = (unsigned)f2bf(W[(size_t)(kb + 2) * N + n]) |
                  ((unsigned)f2bf(W[(size_t)(kb + 3) * N + n]) << 16);
    unsigned p2 = (unsigned)f2bf(W[(size_t)(kb + 4) * N + n]) |
                  ((unsigned)f2bf(W[(size_t)(kb + 5) * N + n]) << 16);
    unsigned p3 = (unsigned)f2bf(W[(size_t)(kb + 6) * N + n]) |
                  ((unsigned)f2bf(W[(size_t)(kb + 7) * N + n]) << 16);
    uint4 v = {p0, p1, p2, p3};
    *(uint4*)(o + (size_t)(sub * 64 + lane) * 8) = v;
}

// ------------------------- conv/BN prep: cw [C][9] -> cwT [9][C]; fold BN scale/bias
__global__ void k_prep_conv(const float* __restrict__ cw,
    const float* __restrict__ bg, const float* __restrict__ bb,
    const float* __restrict__ bm, const float* __restrict__ bv,
    float* __restrict__ cwT, float* __restrict__ bnsc, float* __restrict__ bnbi)
{
    int t = threadIdx.x + blockIdx.x * 256;
    if (t < 9 * CDIM) {
        int tap = t / CDIM, c = t - tap * CDIM;
        cwT[t] = cw[c * 9 + tap];
    }
    if (t < CDIM) {
        float s = bg[t] * rsqrtf(bv[t] + BN_EPS);
        bnsc[t] = s;
        bnbi[t] = bb[t] - bm[t] * s;
    }
}

// ---------------------------------------------------------------- k0: LN1 stats
__global__ void k0_stats(const float* __restrict__ x, float* __restrict__ mv) {
    int t    = blockIdx.x * 4 + (threadIdx.x >> 6);
    int lane = threadIdx.x & 63;
    const float* row = x + (size_t)t * CDIM;
    float e0 = row[lane], e1 = row[lane + 64], e2 = row[lane + 128];
    float s = e0 + e1 + e2;
    for (int o = 32; o; o >>= 1) s += __shfl_xor(s, o);
    float m = s * (1.0f / 192.0f);
    float d0 = e0 - m, d1 = e1 - m, d2 = e2 - m;
    float v = d0*d0 + d1*d1 + d2*d2;
    for (int o = 32; o; o >>= 1) v += __shfl_xor(v, o);
    if (lane == 0) {
        mv[t] = m;
        mv[NTOKALL + t] = 1.0f / sqrtf(v * (1.0f / 192.0f) + LN_EPS);
    }
}

// ------------------------------------------------- k1: LN1 + QKV GEMM (MFMA bf16)
__global__ __launch_bounds__(256) void k1_qkv_mfma(
    const float* __restrict__ x,  const float* __restrict__ mv,
    const float* __restrict__ g1, const float* __restrict__ b1,
    const unsigned short* __restrict__ wsw, const float* __restrict__ qb,
    unsigned short* __restrict__ qkv, int wbase)
{
    const int tid = threadIdx.x;
    const int w = tid >> 6, L = tid & 63, quad = L >> 4, l15 = L & 15;
    const int m0 = blockIdx.x * 64;
    const int Nt = blockIdx.y;                 // 0..2
    int mA = m0 + w * 16 + l15;
    int gt = wbase * NTOK + mA;
    int wg = gt / 49, tok = gt - wg * 49;
    int bb = wg >> 6, wrem = wg & 63;
    int rr = tok / 7, cc = tok - rr * 7;
    int xrow = bb * NPIX + ((wrem >> 3) * 7 + rr) * 56 + (wrem & 7) * 7 + cc;
    float mean = mv[xrow], rstd = mv[NTOKALL + xrow];
    const float* xr = x + (size_t)xrow * CDIM;
    bf16x8 a[6];
#pragma unroll
    for (int kk = 0; kk < 6; ++kk) {
        int c0 = kk * 32 + quad * 8;
        float4 xv0 = *(const float4*)&xr[c0], xv1 = *(const float4*)&xr[c0 + 4];
        float4 gv0 = *(const float4*)&g1[c0], gv1 = *(const float4*)&g1[c0 + 4];
        float4 bv0 = *(const float4*)&b1[c0], bv1 = *(const float4*)&b1[c0 + 4];
        bf16x8 av;
        av[0] = (short)f2bf((xv0.x - mean) * rstd * gv0.x + bv0.x);
        av[1] = (short)f2bf((xv0.y - mean) * rstd * gv0.y + bv0.y);
        av[2] = (short)f2bf((xv0.z - mean) * rstd * gv0.z + bv0.z);
        av[3] = (short)f2bf((xv0.w - mean) * rstd * gv0.w + bv0.w);
        av[4] = (short)f2bf((xv1.x - mean) * rstd * gv1.x + bv1.x);
        av[5] = (short)f2bf((xv1.y - mean) * rstd * gv1.y + bv1.y);
        av[6] = (short)f2bf((xv1.z - mean) * rstd * gv1.z + bv1.z);
        av[7] = (short)f2bf((xv1.w - mean) * rstd * gv1.w + bv1.w);
        a[kk] = av;
    }
    f32x4 acc[12];
#pragma unroll
    for (int nf = 0; nf < 12; ++nf) acc[nf] = (f32x4){0.f, 0.f, 0.f, 0.f};
    const bf16x8* B = (const bf16x8*)wsw;
#pragma unroll
    for (int kk = 0; kk < 6; ++kk) {
#pragma unroll
        for (int nf = 0; nf < 12; ++nf) {
            bf16x8 bfr = B[(size_t)((Nt * 12 + nf) * 6 + kk) * 64 + L];
            acc[nf] = __builtin_amdgcn_mfma_f32_16x16x32_bf16(a[kk], bfr, acc[nf], 0, 0, 0);
        }
    }
    float qbv[12];
#pragma unroll
    for (int nf = 0; nf < 12; ++nf) qbv[nf] = qb[Nt * 192 + nf * 16 + l15];
#pragma unroll
    for (int i = 0; i < 4; ++i) {
        int mrow = m0 + w * 16 + quad * 4 + i;
        int wrel = mrow / 49, tokr = mrow - wrel * 49;
        unsigned short* obase = qkv + (size_t)wrel * WSTR + tokr * 32;
#pragma unroll
        for (int nf = 0; nf < 12; ++nf) {
            int n = Nt * 192 + nf * 16 + l15;
            int h = n / 96, rem = n - h * 96;
            int part = rem >> 5, d = rem & 31;
            obase[(size_t)(part * 6 + h) * 1568 + d] = f2bf(acc[nf][i] + qbv[nf]);
        }
    }
}

// ----------------------------------------------- k2: windowed attention (head pair)
__global__ __launch_bounds__(128) void k2_attn(
    unsigned short* __restrict__ qkv, const float* __restrict__ abias)
{
    __shared__ float kv[6272];   // [kv part(2)][h(2)][tok 49][d 32], f32
    const int wrel = blockIdx.x / 3;
    const int pair = blockIdx.x - wrel * 3;
    const int h0 = pair * 2;
    unsigned short* base = qkv + (size_t)wrel * WSTR;
    for (int idx = threadIdx.x; idx < 784; idx += 128) {   // 8 elems each
        int part = idx / 392;
        int rem  = idx - part * 392;
        int h    = rem / 196;
        int off8 = rem - h * 196;
        bf16x8 v = *(const bf16x8*)&base[(size_t)((part + 1) * 6 + h0 + h) * 1568 + off8 * 8];
        float* dst = &kv[((part * 2 + h) * 196 + off8) * 8];
        float4 f0 = {bf2f((unsigned short)v[0]), bf2f((unsigned short)v[1]),
                     bf2f((unsigned short)v[2]), bf2f((unsigned short)v[3])};
        float4 f1 = {bf2f((unsigned short)v[4]), bf2f((unsigned short)v[5]),
                     bf2f((unsigned short)v[6]), bf2f((unsigned short)v[7])};
        *(float4*)&dst[0] = f0;
        *(float4*)&dst[4] = f1;
    }
    __syncthreads();
    const int item = threadIdx.x;
    if (item >= 98) return;
    const int h = item / 49;
    const int row = item - h * 49;
    const int hg = h0 + h;
    unsigned short* qptr = base + (size_t)hg * 1568 + row * 32;
    float4 q4[8];
#pragma unroll
    for (int dq2 = 0; dq2 < 4; ++dq2) {
        bf16x8 v = *(const bf16x8*)&qptr[dq2 * 8];
        q4[dq2 * 2]     = (float4){bf2f((unsigned short)v[0]), bf2f((unsigned short)v[1]),
                                   bf2f((unsigned short)v[2]), bf2f((unsigned short)v[3])};
        q4[dq2 * 2 + 1] = (float4){bf2f((unsigned short)v[4]), bf2f((unsigned short)v[5]),
                                   bf2f((unsigned short)v[6]), bf2f((unsigned short)v[7])};
    }
    const int rr = row / 7, rc = row - rr * 7;
    const float scale = 0.17677669529663687f;   // 32^-0.5
    const float* kbase = &kv[(h * 49) * 32];
    const float* vbase = &kv[(98 + h * 49) * 32];
    float s[49];
    for (int j = 0; j < 49; ++j) {
        const float* kr = kbase + j * 32;
        float4 a = {0, 0, 0, 0};
#pragma unroll
        for (int dq = 0; dq < 8; ++dq) {
            float4 k4 = *(const float4*)&kr[dq * 4];
            a.x += q4[dq].x * k4.x; a.y += q4[dq].y * k4.y;
            a.z += q4[dq].z * k4.z; a.w += q4[dq].w * k4.w;
        }
        int jr = j / 7, jc = j - jr * 7;
        int dy = rr > jr ? rr - jr : jr - rr;
        int dx = rc > jc ? rc - jc : jc - rc;
        s[j] = (a.x + a.y + a.z + a.w) * scale + abias[hg * 49 + dy * 7 + dx];
    }
    float mx = s[0];
    for (int j = 1; j < 49; ++j) mx = fmaxf(mx, s[j]);
    float sum = 0.0f;
    for (int j = 0; j < 49; ++j) { s[j] = __expf(s[j] - mx); sum += s[j]; }
    float rinv = 1.0f / sum;
    float4 o[8] = {};
    for (int j = 0; j < 49; ++j) {
        float p = s[j];
        const float* vr = vbase + j * 32;
#pragma unroll
        for (int dq = 0; dq < 8; ++dq) {
            float4 v4 = *(const float4*)&vr[dq * 4];
            o[dq].x += p * v4.x; o[dq].y += p * v4.y;
            o[dq].z += p * v4.z; o[dq].w += p * v4.w;
        }
    }
#pragma unroll
    for (int dq = 0; dq < 8; ++dq) {
        uint2 pk;
        pk.x = (unsigned)f2bf(o[dq].x * rinv) | ((unsigned)f2bf(o[dq].y * rinv) << 16);
        pk.y = (unsigned)f2bf(o[dq].z * rinv) | ((unsigned)f2bf(o[dq].w * rinv) << 16);
        *(uint2*)&qptr[dq * 4] = pk;       // overwrite q slot (own row only)
    }
}

// --------------------------- k3: proj GEMM (MFMA) + bias + residual + window reverse
__global__ __launch_bounds__(256) void k3_proj_mfma(
    const unsigned short* __restrict__ qkv, const float* __restrict__ x,
    const unsigned short* __restrict__ wsw, const float* __restrict__ pb,
    float* __restrict__ x1, int wbase)
{
    const int tid = threadIdx.x;
    const int w = tid >> 6, L = tid & 63, quad = L >> 4, l15 = L & 15;
    const int m0 = blockIdx.x * 64;
    const int Nt = blockIdx.y;                 // 0..2, 64 cols each
    int mA = m0 + w * 16 + l15;
    int wrelA = mA / 49, tokA = mA - wrelA * 49;
    const unsigned short* ar = qkv + (size_t)wrelA * WSTR + tokA * 32 + quad * 8;
    bf16x8 a[6];
#pragma unroll
    for (int kk = 0; kk < 6; ++kk)             // head = kk
        a[kk] = *(const bf16x8*)&ar[(size_t)kk * 1568];
    f32x4 acc[4];
#pragma unroll
    for (int nf = 0; nf < 4; ++nf) acc[nf] = (f32x4){0.f, 0.f, 0.f, 0.f};
    const bf16x8* B = (const bf16x8*)wsw;
#pragma unroll
    for (int kk = 0; kk < 6; ++kk) {
#pragma unroll
        for (int nf = 0; nf < 4; ++nf) {
            bf16x8 bfr = B[(size_t)((Nt * 4 + nf) * 6 + kk) * 64 + L];
            acc[nf] = __builtin_amdgcn_mfma_f32_16x16x32_bf16(a[kk], bfr, acc[nf], 0, 0, 0);
        }
    }
    float pbv[4];
#pragma unroll
    for (int nf = 0; nf < 4; ++nf) pbv[nf] = pb[Nt * 64 + nf * 16 + l15];
#pragma unroll
    for (int i = 0; i < 4; ++i) {
        int mrow = m0 + w * 16 + quad * 4 + i;
        int wrel = mrow / 49, tokr = mrow - wrel * 49;
        int wg = wbase + wrel;
        int bb = wg >> 6, wrem = wg & 63;
        int r = tokr / 7, c = tokr - r * 7;
        size_t xoff = ((size_t)(bb * NPIX + ((wrem >> 3) * 7 + r) * 56 + (wrem & 7) * 7 + c)) * CDIM;
#pragma unroll
        for (int nf = 0; nf < 4; ++nf) {
            int col = Nt * 64 + nf * 16 + l15;
            x1[xoff + col] = acc[nf][i] + pbv[nf] + x[xoff + col];
        }
    }
}

// ---------------------- k4: depthwise conv3x3 + BN + LN2 stats (1 wave per token)
// All loads are lane-coalesced float4 (cwT is [tap][C], BN prefolded) -- the
// R2 profile showed the [C][9] scattered cw loads cost ~1600 L1 lines/wave.
__global__ __launch_bounds__(256) void k4_convln(
    const float* __restrict__ x1, const float* __restrict__ cwT,
    const float* __restrict__ bnsc, const float* __restrict__ bnbi,
    float* __restrict__ x2, float* __restrict__ mv)
{
    const int w = threadIdx.x >> 6, lane = threadIdx.x & 63;
    const int t = blockIdx.x * 4 + w;
    const int b = t / NPIX, l = t - b * NPIX;
    const int yy = l / 56, xx = l - yy * 56;
    const bool act = lane < 48;
    const int c0 = lane * 4;
    float4 o = {0, 0, 0, 0};
    if (act) {
        const float* xb = x1 + (size_t)b * NPIX * CDIM;
        float4 acc = {0, 0, 0, 0};
#pragma unroll
        for (int dy = -1; dy <= 1; ++dy) {
            int y2 = yy + dy;
            if ((unsigned)y2 >= 56u) continue;
#pragma unroll
            for (int dx = -1; dx <= 1; ++dx) {
                int x2c = xx + dx;
                if ((unsigned)x2c >= 56u) continue;
                float4 v = *(const float4*)&xb[(size_t)(y2 * 56 + x2c) * CDIM + c0];
                int tap = (dy + 1) * 3 + (dx + 1);
                float4 wt = *(const float4*)&cwT[tap * CDIM + c0];
                acc.x += v.x * wt.x;
                acc.y += v.y * wt.y;
                acc.z += v.z * wt.z;
                acc.w += v.w * wt.w;
            }
        }
        float4 sc = *(const float4*)&bnsc[c0];
        float4 bi = *(const float4*)&bnbi[c0];
        o.x = acc.x * sc.x + bi.x;
        o.y = acc.y * sc.y + bi.y;
        o.z = acc.z * sc.z + bi.z;
        o.w = acc.w * sc.w + bi.w;
        *(float4*)&x2[(size_t)t * CDIM + c0] = o;
    }
    // LN2 stats (two-pass, butterfly gives sum to all lanes)
    float s = o.x + o.y + o.z + o.w;
    for (int off = 32; off; off >>= 1) s += __shfl_xor(s, off);
    float m = s * (1.0f / 192.0f);
    float d0 = o.x - m, d1 = o.y - m, d2 = o.z - m, d3 = o.w - m;
    float v2 = act ? (d0*d0 + d1*d1 + d2*d2 + d3*d3) : 0.0f;
    for (int off = 32; off; off >>= 1) v2 += __shfl_xor(v2, off);
    if (lane == 0) {
        mv[t] = m;
        mv[NTOKALL + t] = 1.0f / sqrtf(v2 * (1.0f / 192.0f) + LN_EPS);
    }
}

// --------------- k5: LN2 + FC1 + GELU + FC2 + residual (MFMA, LDS-staged A-frags)
// FC2 nf-split across waves (R2). GELU = exact erff (R1 trans-op & R4 LDS-LUT
// variants both stall-regressed at this kernel's low occupancy). LDS shrunk
// 40KB -> 32KB (hidden chunk 128 -> 64 cols, 12 iters) to raise blocks/CU:
// R3/R4 profiles show occupancy 18-25% (~1.5-2 blocks/CU), LDS-limited.
__global__ __launch_bounds__(256) void k5_mlp_mfma(
    const float* __restrict__ x2, const float* __restrict__ mv2,
    const float* __restrict__ g2, const float* __restrict__ b2,
    const unsigned short* __restrict__ w1sw, const float* __restrict__ fb1,
    const unsigned short* __restrict__ w2sw, const float* __restrict__ fb2,
    float* __restrict__ out)
{
    __shared__ unsigned short aFrag[24 * 512];   // [mf 4][kk 6][lane 64][8 bf16] = 24KB
    __shared__ unsigned short hsw[8 * 512];      // hidden chunk 64x64: [ksub 2][mf 4][lane 64][8] = 8KB
    const int tid = threadIdx.x;
    const int w = tid >> 6, L = tid & 63, quad = L >> 4, l15 = L & 15;
    const int m0 = blockIdx.x * 64;
    // ---- build LN2(x2) A-fragments into LDS (cooperative, 6 slots/thread)
#pragma unroll
    for (int rsl = 0; rsl < 6; ++rsl) {
        int s = tid + 256 * rsl;                 // 0..1535
        int mf = s / 384, rem = s - mf * 384;
        int kk = rem >> 6, La = rem & 63;
        int row = m0 + mf * 16 + (La & 15);
        int c0 = kk * 32 + (La >> 4) * 8;
        float mm = mv2[row], rs = mv2[NTOKALL + row];
        const float* xr = x2 + (size_t)row * CDIM + c0;
        float4 xv0 = *(const float4*)&xr[0], xv1 = *(const float4*)&xr[4];
        float4 gv0 = *(const float4*)&g2[c0], gv1 = *(const float4*)&g2[c0 + 4];
        float4 bv0 = *(const float4*)&b2[c0], bv1 = *(const float4*)&b2[c0 + 4];
        bf16x8 av;
        av[0] = (short)f2bf((xv0.x - mm) * rs * gv0.x + bv0.x);
        av[1] = (short)f2bf((xv0.y - mm) * rs * gv0.y + bv0.y);
        av[2] = (short)f2bf((xv0.z - mm) * rs * gv0.z + bv0.z);
        av[3] = (short)f2bf((xv0.w - mm) * rs * gv0.w + bv0.w);
        av[4] = (short)f2bf((xv1.x - mm) * rs * gv1.x + bv1.x);
        av[5] = (short)f2bf((xv1.y - mm) * rs * gv1.y + bv1.y);
        av[6] = (short)f2bf((xv1.z - mm) * rs * gv1.z + bv1.z);
        av[7] = (short)f2bf((xv1.w - mm) * rs * gv1.w + bv1.w);
        *(bf16x8*)&aFrag[(size_t)s * 8] = av;
    }
    __syncthreads();

    f32x4 acc2[4][3];    // [mf][nf]  cols = w*48 + nf*16 + l15
#pragma unroll
    for (int mf = 0; mf < 4; ++mf)
#pragma unroll
        for (int nf = 0; nf < 3; ++nf) acc2[mf][nf] = (f32x4){0.f, 0.f, 0.f, 0.f};
    const bf16x8* B1 = (const bf16x8*)w1sw;
    const bf16x8* B2 = (const bf16x8*)w2sw;

    const int sbase = w >> 1;                      // hsw k-subtile this wave fills
    const int quadp = ((w & 1) << 1) | (l15 >> 3); // dest quad within subtile
    for (int ch = 0; ch < 12; ++ch) {
        // ---- FC1: hidden cols [ch*64 + 16w, +16) for all 64 rows
        f32x4 acc1[4];
#pragma unroll
        for (int mf = 0; mf < 4; ++mf) acc1[mf] = (f32x4){0.f, 0.f, 0.f, 0.f};
#pragma unroll
        for (int kk = 0; kk < 6; ++kk) {
            bf16x8 bfr = B1[(size_t)((ch * 4 + w) * 6 + kk) * 64 + L];
#pragma unroll
            for (int mf = 0; mf < 4; ++mf) {
                bf16x8 av = *(const bf16x8*)&aFrag[(size_t)((mf * 6 + kk) * 64 + L) * 8];
                acc1[mf] = __builtin_amdgcn_mfma_f32_16x16x32_bf16(av, bfr, acc1[mf], 0, 0, 0);
            }
        }
        __syncthreads();   // prior FC2 reads of hsw complete
        // ---- GELU + store hidden in A-frag layout
        // col = ch*64 + 16w + l15 -> k-in-chunk: ksub=w>>1, quad'=((w&1)<<1)|(l15>>3), j=l15&7
        float bias = fb1[ch * 64 + 16 * w + l15];
#pragma unroll
        for (int mf = 0; mf < 4; ++mf) {
#pragma unroll
            for (int i = 0; i < 4; ++i) {
                float h = acc1[mf][i] + bias;
                h = h * 0.5f * (1.0f + erff(h * 0.70710678118654752f));
                int Ls = (quad * 4 + i) | (quadp << 4);
                hsw[(sbase * 4 + mf) * 512 + Ls * 8 + (l15 & 7)] = f2bf(h);
            }
        }
        __syncthreads();
        // ---- FC2 partial (nf-split): acc2[mf][nf] over this chunk's 64 k
#pragma unroll
        for (int kk2 = 0; kk2 < 2; ++kk2) {
            bf16x8 a2[4];
#pragma unroll
            for (int mf = 0; mf < 4; ++mf)
                a2[mf] = *(const bf16x8*)&hsw[(size_t)((kk2 * 4 + mf) * 512) + (size_t)L * 8];
#pragma unroll
            for (int nf = 0; nf < 3; ++nf) {
                bf16x8 bfr = B2[(size_t)((w * 3 + nf) * 24 + ch * 2 + kk2) * 64 + L];
#pragma unroll
                for (int mf = 0; mf < 4; ++mf)
                    acc2[mf][nf] = __builtin_amdgcn_mfma_f32_16x16x32_bf16(a2[mf], bfr, acc2[mf][nf], 0, 0, 0);
            }
        }
    }
    // ---- epilogue: + fc2_b + residual(x2); wave w covers cols [48w, 48w+48)
    float fb2v[3];
#pragma unroll
    for (int nf = 0; nf < 3; ++nf) fb2v[nf] = fb2[w * 48 + nf * 16 + l15];
#pragma unroll
    for (int mf = 0; mf < 4; ++mf) {
#pragma unroll
        for (int i = 0; i < 4; ++i) {
            int row = m0 + mf * 16 + quad * 4 + i;
            const float* xr = x2 + (size_t)row * CDIM;
            float* orow = out + (size_t)row * CDIM;
#pragma unroll
            for (int nf = 0; nf < 3; ++nf) {
                int col = w * 48 + nf * 16 + l15;
                orow[col] = acc2[mf][nf][i] + fb2v[nf] + xr[col];
            }
        }
    }
}

// ------------------------------------------------------------------- launcher
extern "C" void kernel_launch(void* const* d_in, const int* in_sizes, int n_in,
                              void* d_out, int out_size, void* d_ws, size_t ws_size,
                              hipStream_t stream) {
    const float* x     = (const float*)d_in[0];
    const float* g1    = (const float*)d_in[1];
    const float* b1    = (const float*)d_in[2];
    const float* qkvw  = (const float*)d_in[3];
    const float* qkvb  = (const float*)d_in[4];
    const float* abias = (const float*)d_in[5];
    const float* projw = (const float*)d_in[6];
    const float* projb = (const float*)d_in[7];
    const float* convw = (const float*)d_in[8];
    const float* bng   = (const float*)d_in[9];
    const float* bnb   = (const float*)d_in[10];
    const float* bnm   = (const float*)d_in[11];
    const float* bnv   = (const float*)d_in[12];
    const float* g2    = (const float*)d_in[13];
    const float* b2    = (const float*)d_in[14];
    const float* fc1w  = (const float*)d_in[15];
    const float* fc1b  = (const float*)d_in[16];
    const float* fc2w  = (const float*)d_in[17];
    const float* fc2b  = (const float*)d_in[18];
    float* out = (float*)d_out;

    // ws layout (floats):
    //   [0, 19267584)            qkv bf16 chunk scratch (28.9MB used) / later x2 fp32 (77MB)
    //   [19267584, 19468288)     LN mean/rstd (LN1, then overwritten by LN2 stats in k4)
    //   [19468288, 19689472)     swizzled bf16 weights (884,736 B)
    //   [19689472, ...)          cwT (1728) + bnsc (192) + bnbi (192)
    float* wsf   = (float*)d_ws;
    unsigned short* qkvws = (unsigned short*)wsf;
    float* x2b   = wsf;
    float* mv    = wsf + 19267584;
    unsigned short* qkvw_sw = (unsigned short*)(wsf + 19468288);
    unsigned short* projw_sw = qkvw_sw + 110592;
    unsigned short* fc1_sw   = projw_sw + 36864;
    unsigned short* fc2_sw   = fc1_sw + 147456;
    float* cwT  = wsf + 19689472;
    float* bnsc = cwT + 1728;
    float* bnbi = bnsc + 192;

    kw_swz<<<(216 * 64 + 255) / 256, 256, 0, stream>>>(qkvw, qkvw_sw, CDIM, QKVN);
    kw_swz<<<(72  * 64 + 255) / 256, 256, 0, stream>>>(projw, projw_sw, CDIM, CDIM);
    kw_swz<<<(288 * 64 + 255) / 256, 256, 0, stream>>>(fc1w, fc1_sw, CDIM, HIDDEN);
    kw_swz<<<(288 * 64 + 255) / 256, 256, 0, stream>>>(fc2w, fc2_sw, HIDDEN, CDIM);
    k_prep_conv<<<7, 256, 0, stream>>>(convw, bng, bnb, bnm, bnv, cwT, bnsc, bnbi);

    k0_stats<<<NTOKALL / 4, 256, 0, stream>>>(x, mv);
    for (int chunk = 0; chunk < NCHUNK; ++chunk) {
        int wbase = chunk * CHUNKW;
        k1_qkv_mfma<<<dim3(CHUNKM / 64, 3), 256, 0, stream>>>(
            x, mv, g1, b1, qkvw_sw, qkvb, qkvws, wbase);
        k2_attn<<<CHUNKW * 3, 128, 0, stream>>>(qkvws, abias);
        k3_proj_mfma<<<dim3(CHUNKM / 64, 3), 256, 0, stream>>>(
            qkvws, x, projw_sw, projb, out, wbase);
    }
    k4_convln<<<NTOKALL / 4, 256, 0, stream>>>(out, cwT, bnsc, bnbi, x2b, mv);
    k5_mlp_mfma<<<NTOKALL / 64, 256, 0, stream>>>(
        x2b, mv, g2, b2, fc1_sw, fc1b, fc2_sw, fc2b, out);
}

// Round 6
// 856.929 us; speedup vs baseline: 1.0653x; 1.0095x over previous
//
#include <hip/hip_runtime.h>

// Problem constants
#define CDIM   192
#define NHEADS 6
#define KDIM   32
#define NTOK   49          // tokens per window (7x7)
#define NPIX   3136        // 56*56
#define NB     32
#define NWIN   2048        // 32 * 8 * 8
#define CHUNKW 512         // windows per chunk
#define NCHUNK 4
#define CHUNKM (CHUNKW*NTOK)   // 25088
#define QKVN   576
#define HIDDEN 768
#define LN_EPS 1e-5f
#define BN_EPS 1e-5f
#define WSTR   28224       // 3*6*49*32 bf16 elements per window in qkv scratch
#define NTOKALL 100352     // 32*3136

typedef __attribute__((ext_vector_type(8))) short bf16x8;   // 8 bf16 = 4 VGPRs
typedef __attribute__((ext_vector_type(4))) float f32x4;

__device__ __forceinline__ unsigned short f2bf(float f) {
    unsigned u = __float_as_uint(f);
    return (unsigned short)((u + 0x7FFFu + ((u >> 16) & 1u)) >> 16);   // RNE
}
__device__ __forceinline__ float bf2f(unsigned short s) {
    return __uint_as_float(((unsigned)s) << 16);
}

// Fast exact-GELU: 0.5*x*(1+erf(x/sqrt(2))) with Abramowitz-Stegun 7.1.26 erf
// (|erf err| <= 1.5e-7; validated in R1). ~10 full-rate FMA + 2 trans ops vs
// ~80 branchy instrs in ocml erff. Safe now that FC2 is 1:4 load:MFMA (R2) --
// R1's regression was the then-broken FC2 losing its latency cover, not this.
__device__ __forceinline__ float fast_gelu(float x) {
    float ax = fabsf(x);
    float t  = __builtin_amdgcn_rcpf(fmaf(0.23164190f, ax, 1.0f)); // 1/(1+p*ax/sqrt2)
    float p  = fmaf(t, 1.061405429f, -1.453152027f);
    p = fmaf(t, p, 1.421413741f);
    p = fmaf(t, p, -0.284496736f);
    p = fmaf(t, p, 0.254829592f);
    p = p * t;
    float e  = __expf(-0.5f * x * x);
    float q  = ax * p * e;
    return 0.5f * (x + ax - q);              // branch-free both signs
}

// ------------------------------------------- weight swizzle: fp32 KxN -> bf16 frags
// frag layout: subtile id = (n0/16)*(K/32) + (k0/32); lane L holds
// W[k0 + (L>>4)*8 + j][n0 + (L&15)], j=0..7, stored as 16B per lane.
__global__ void kw_swz(const float* __restrict__ W, unsigned short* __restrict__ o,
                       int K, int N) {
    int t = blockIdx.x * 256 + threadIdx.x;
    int lane = t & 63, sub = t >> 6;
    int ksub = K >> 5;
    int total = (N >> 4) * ksub;
    if (sub >= total) return;
    int nfr = sub / ksub, kk = sub - nfr * ksub;
    int n = nfr * 16 + (lane & 15);
    int kb = kk * 32 + (lane >> 4) * 8;
    unsigned p0 = (unsigned)f2bf(W[(size_t)(kb + 0) * N + n]) |
                  ((unsigned)f2bf(W[(size_t)(kb + 1) * N + n]) << 16);
    unsigned p1 = (unsigned)f2bf(W[(size_t)(kb + 2) * N + n]) |
                  ((unsigned)f2bf(W[(size_t)(kb + 3) * N + n]) << 16);
    unsigned p2 = (unsigned)f2bf(W[(size_t)(kb + 4) * N + n]) |
                  ((unsigned)f2bf(W[(size_t)(kb + 5) * N + n]) << 16);
    unsigned p3 = (unsigned)f2bf(W[(size_t)(kb + 6) * N + n]) |
                  ((unsigned)f2bf(W[(size_t)(kb + 7) * N + n]) << 16);
    uint4 v = {p0, p1, p2, p3};
    *(uint4*)(o + (size_t)(sub * 64 + lane) * 8) = v;
}

// ------------------------- conv/BN prep: cw [C][9] -> cwT [9][C]; fold BN scale/bias
__global__ void k_prep_conv(const float* __restrict__ cw,
    const float* __restrict__ bg, const float* __restrict__ bb,
    const float* __restrict__ bm, const float* __restrict__ bv,
    float* __restrict__ cwT, float* __restrict__ bnsc, float* __restrict__ bnbi)
{
    int t = threadIdx.x + blockIdx.x * 256;
    if (t < 9 * CDIM) {
        int tap = t / CDIM, c = t - tap * CDIM;
        cwT[t] = cw[c * 9 + tap];
    }
    if (t < CDIM) {
        float s = bg[t] * rsqrtf(bv[t] + BN_EPS);
        bnsc[t] = s;
        bnbi[t] = bb[t] - bm[t] * s;
    }
}

// ---------------------------------------------------------------- k0: LN1 stats
__global__ void k0_stats(const float* __restrict__ x, float* __restrict__ mv) {
    int t    = blockIdx.x * 4 + (threadIdx.x >> 6);
    int lane = threadIdx.x & 63;
    const float* row = x + (size_t)t * CDIM;
    float e0 = row[lane], e1 = row[lane + 64], e2 = row[lane + 128];
    float s = e0 + e1 + e2;
    for (int o = 32; o; o >>= 1) s += __shfl_xor(s, o);
    float m = s * (1.0f / 192.0f);
    float d0 = e0 - m, d1 = e1 - m, d2 = e2 - m;
    float v = d0*d0 + d1*d1 + d2*d2;
    for (int o = 32; o; o >>= 1) v += __shfl_xor(v, o);
    if (lane == 0) {
        mv[t] = m;
        mv[NTOKALL + t] = 1.0f / sqrtf(v * (1.0f / 192.0f) + LN_EPS);
    }
}

// ------------------------------------------------- k1: LN1 + QKV GEMM (MFMA bf16)
__global__ __launch_bounds__(256) void k1_qkv_mfma(
    const float* __restrict__ x,  const float* __restrict__ mv,
    const float* __restrict__ g1, const float* __restrict__ b1,
    const unsigned short* __restrict__ wsw, const float* __restrict__ qb,
    unsigned short* __restrict__ qkv, int wbase)
{
    const int tid = threadIdx.x;
    const int w = tid >> 6, L = tid & 63, quad = L >> 4, l15 = L & 15;
    const int m0 = blockIdx.x * 64;
    const int Nt = blockIdx.y;                 // 0..2
    int mA = m0 + w * 16 + l15;
    int gt = wbase * NTOK + mA;
    int wg = gt / 49, tok = gt - wg * 49;
    int bb = wg >> 6, wrem = wg & 63;
    int rr = tok / 7, cc = tok - rr * 7;
    int xrow = bb * NPIX + ((wrem >> 3) * 7 + rr) * 56 + (wrem & 7) * 7 + cc;
    float mean = mv[xrow], rstd = mv[NTOKALL + xrow];
    const float* xr = x + (size_t)xrow * CDIM;
    bf16x8 a[6];
#pragma unroll
    for (int kk = 0; kk < 6; ++kk) {
        int c0 = kk * 32 + quad * 8;
        float4 xv0 = *(const float4*)&xr[c0], xv1 = *(const float4*)&xr[c0 + 4];
        float4 gv0 = *(const float4*)&g1[c0], gv1 = *(const float4*)&g1[c0 + 4];
        float4 bv0 = *(const float4*)&b1[c0], bv1 = *(const float4*)&b1[c0 + 4];
        bf16x8 av;
        av[0] = (short)f2bf((xv0.x - mean) * rstd * gv0.x + bv0.x);
        av[1] = (short)f2bf((xv0.y - mean) * rstd * gv0.y + bv0.y);
        av[2] = (short)f2bf((xv0.z - mean) * rstd * gv0.z + bv0.z);
        av[3] = (short)f2bf((xv0.w - mean) * rstd * gv0.w + bv0.w);
        av[4] = (short)f2bf((xv1.x - mean) * rstd * gv1.x + bv1.x);
        av[5] = (short)f2bf((xv1.y - mean) * rstd * gv1.y + bv1.y);
        av[6] = (short)f2bf((xv1.z - mean) * rstd * gv1.z + bv1.z);
        av[7] = (short)f2bf((xv1.w - mean) * rstd * gv1.w + bv1.w);
        a[kk] = av;
    }
    f32x4 acc[12];
#pragma unroll
    for (int nf = 0; nf < 12; ++nf) acc[nf] = (f32x4){0.f, 0.f, 0.f, 0.f};
    const bf16x8* B = (const bf16x8*)wsw;
#pragma unroll
    for (int kk = 0; kk < 6; ++kk) {
#pragma unroll
        for (int nf = 0; nf < 12; ++nf) {
            bf16x8 bfr = B[(size_t)((Nt * 12 + nf) * 6 + kk) * 64 + L];
            acc[nf] = __builtin_amdgcn_mfma_f32_16x16x32_bf16(a[kk], bfr, acc[nf], 0, 0, 0);
        }
    }
    float qbv[12];
#pragma unroll
    for (int nf = 0; nf < 12; ++nf) qbv[nf] = qb[Nt * 192 + nf * 16 + l15];
#pragma unroll
    for (int i = 0; i < 4; ++i) {
        int mrow = m0 + w * 16 + quad * 4 + i;
        int wrel = mrow / 49, tokr = mrow - wrel * 49;
        unsigned short* obase = qkv + (size_t)wrel * WSTR + tokr * 32;
#pragma unroll
        for (int nf = 0; nf < 12; ++nf) {
            int n = Nt * 192 + nf * 16 + l15;
            int h = n / 96, rem = n - h * 96;
            int part = rem >> 5, d = rem & 31;
            obase[(size_t)(part * 6 + h) * 1568 + d] = f2bf(acc[nf][i] + qbv[nf]);
        }
    }
}

// ----------------------------------------------- k2: windowed attention (head pair)
__global__ __launch_bounds__(128) void k2_attn(
    unsigned short* __restrict__ qkv, const float* __restrict__ abias)
{
    __shared__ float kv[6272];   // [kv part(2)][h(2)][tok 49][d 32], f32
    const int wrel = blockIdx.x / 3;
    const int pair = blockIdx.x - wrel * 3;
    const int h0 = pair * 2;
    unsigned short* base = qkv + (size_t)wrel * WSTR;
    for (int idx = threadIdx.x; idx < 784; idx += 128) {   // 8 elems each
        int part = idx / 392;
        int rem  = idx - part * 392;
        int h    = rem / 196;
        int off8 = rem - h * 196;
        bf16x8 v = *(const bf16x8*)&base[(size_t)((part + 1) * 6 + h0 + h) * 1568 + off8 * 8];
        float* dst = &kv[((part * 2 + h) * 196 + off8) * 8];
        float4 f0 = {bf2f((unsigned short)v[0]), bf2f((unsigned short)v[1]),
                     bf2f((unsigned short)v[2]), bf2f((unsigned short)v[3])};
        float4 f1 = {bf2f((unsigned short)v[4]), bf2f((unsigned short)v[5]),
                     bf2f((unsigned short)v[6]), bf2f((unsigned short)v[7])};
        *(float4*)&dst[0] = f0;
        *(float4*)&dst[4] = f1;
    }
    __syncthreads();
    const int item = threadIdx.x;
    if (item >= 98) return;
    const int h = item / 49;
    const int row = item - h * 49;
    const int hg = h0 + h;
    unsigned short* qptr = base + (size_t)hg * 1568 + row * 32;
    float4 q4[8];
#pragma unroll
    for (int dq2 = 0; dq2 < 4; ++dq2) {
        bf16x8 v = *(const bf16x8*)&qptr[dq2 * 8];
        q4[dq2 * 2]     = (float4){bf2f((unsigned short)v[0]), bf2f((unsigned short)v[1]),
                                   bf2f((unsigned short)v[2]), bf2f((unsigned short)v[3])};
        q4[dq2 * 2 + 1] = (float4){bf2f((unsigned short)v[4]), bf2f((unsigned short)v[5]),
                                   bf2f((unsigned short)v[6]), bf2f((unsigned short)v[7])};
    }
    const int rr = row / 7, rc = row - rr * 7;
    const float scale = 0.17677669529663687f;   // 32^-0.5
    const float* kbase = &kv[(h * 49) * 32];
    const float* vbase = &kv[(98 + h * 49) * 32];
    float s[49];
    for (int j = 0; j < 49; ++j) {
        const float* kr = kbase + j * 32;
        float4 a = {0, 0, 0, 0};
#pragma unroll
        for (int dq = 0; dq < 8; ++dq) {
            float4 k4 = *(const float4*)&kr[dq * 4];
            a.x += q4[dq].x * k4.x; a.y += q4[dq].y * k4.y;
            a.z += q4[dq].z * k4.z; a.w += q4[dq].w * k4.w;
        }
        int jr = j / 7, jc = j - jr * 7;
        int dy = rr > jr ? rr - jr : jr - rr;
        int dx = rc > jc ? rc - jc : jc - rc;
        s[j] = (a.x + a.y + a.z + a.w) * scale + abias[hg * 49 + dy * 7 + dx];
    }
    float mx = s[0];
    for (int j = 1; j < 49; ++j) mx = fmaxf(mx, s[j]);
    float sum = 0.0f;
    for (int j = 0; j < 49; ++j) { s[j] = __expf(s[j] - mx); sum += s[j]; }
    float rinv = 1.0f / sum;
    float4 o[8] = {};
    for (int j = 0; j < 49; ++j) {
        float p = s[j];
        const float* vr = vbase + j * 32;
#pragma unroll
        for (int dq = 0; dq < 8; ++dq) {
            float4 v4 = *(const float4*)&vr[dq * 4];
            o[dq].x += p * v4.x; o[dq].y += p * v4.y;
            o[dq].z += p * v4.z; o[dq].w += p * v4.w;
        }
    }
#pragma unroll
    for (int dq = 0; dq < 8; ++dq) {
        uint2 pk;
        pk.x = (unsigned)f2bf(o[dq].x * rinv) | ((unsigned)f2bf(o[dq].y * rinv) << 16);
        pk.y = (unsigned)f2bf(o[dq].z * rinv) | ((unsigned)f2bf(o[dq].w * rinv) << 16);
        *(uint2*)&qptr[dq * 4] = pk;       // overwrite q slot (own row only)
    }
}

// --------------------------- k3: proj GEMM (MFMA) + bias + residual + window reverse
__global__ __launch_bounds__(256) void k3_proj_mfma(
    const unsigned short* __restrict__ qkv, const float* __restrict__ x,
    const unsigned short* __restrict__ wsw, const float* __restrict__ pb,
    float* __restrict__ x1, int wbase)
{
    const int tid = threadIdx.x;
    const int w = tid >> 6, L = tid & 63, quad = L >> 4, l15 = L & 15;
    const int m0 = blockIdx.x * 64;
    const int Nt = blockIdx.y;                 // 0..2, 64 cols each
    int mA = m0 + w * 16 + l15;
    int wrelA = mA / 49, tokA = mA - wrelA * 49;
    const unsigned short* ar = qkv + (size_t)wrelA * WSTR + tokA * 32 + quad * 8;
    bf16x8 a[6];
#pragma unroll
    for (int kk = 0; kk < 6; ++kk)             // head = kk
        a[kk] = *(const bf16x8*)&ar[(size_t)kk * 1568];
    f32x4 acc[4];
#pragma unroll
    for (int nf = 0; nf < 4; ++nf) acc[nf] = (f32x4){0.f, 0.f, 0.f, 0.f};
    const bf16x8* B = (const bf16x8*)wsw;
#pragma unroll
    for (int kk = 0; kk < 6; ++kk) {
#pragma unroll
        for (int nf = 0; nf < 4; ++nf) {
            bf16x8 bfr = B[(size_t)((Nt * 4 + nf) * 6 + kk) * 64 + L];
            acc[nf] = __builtin_amdgcn_mfma_f32_16x16x32_bf16(a[kk], bfr, acc[nf], 0, 0, 0);
        }
    }
    float pbv[4];
#pragma unroll
    for (int nf = 0; nf < 4; ++nf) pbv[nf] = pb[Nt * 64 + nf * 16 + l15];
#pragma unroll
    for (int i = 0; i < 4; ++i) {
        int mrow = m0 + w * 16 + quad * 4 + i;
        int wrel = mrow / 49, tokr = mrow - wrel * 49;
        int wg = wbase + wrel;
        int bb = wg >> 6, wrem = wg & 63;
        int r = tokr / 7, c = tokr - r * 7;
        size_t xoff = ((size_t)(bb * NPIX + ((wrem >> 3) * 7 + r) * 56 + (wrem & 7) * 7 + c)) * CDIM;
#pragma unroll
        for (int nf = 0; nf < 4; ++nf) {
            int col = Nt * 64 + nf * 16 + l15;
            x1[xoff + col] = acc[nf][i] + pbv[nf] + x[xoff + col];
        }
    }
}

// ---------------------- k4: depthwise conv3x3 + BN + LN2 stats (1 wave per token)
// All loads are lane-coalesced float4 (cwT is [tap][C], BN prefolded) -- the
// R2 profile showed the [C][9] scattered cw loads cost ~1600 L1 lines/wave.
__global__ __launch_bounds__(256) void k4_convln(
    const float* __restrict__ x1, const float* __restrict__ cwT,
    const float* __restrict__ bnsc, const float* __restrict__ bnbi,
    float* __restrict__ x2, float* __restrict__ mv)
{
    const int w = threadIdx.x >> 6, lane = threadIdx.x & 63;
    const int t = blockIdx.x * 4 + w;
    const int b = t / NPIX, l = t - b * NPIX;
    const int yy = l / 56, xx = l - yy * 56;
    const bool act = lane < 48;
    const int c0 = lane * 4;
    float4 o = {0, 0, 0, 0};
    if (act) {
        const float* xb = x1 + (size_t)b * NPIX * CDIM;
        float4 acc = {0, 0, 0, 0};
#pragma unroll
        for (int dy = -1; dy <= 1; ++dy) {
            int y2 = yy + dy;
            if ((unsigned)y2 >= 56u) continue;
#pragma unroll
            for (int dx = -1; dx <= 1; ++dx) {
                int x2c = xx + dx;
                if ((unsigned)x2c >= 56u) continue;
                float4 v = *(const float4*)&xb[(size_t)(y2 * 56 + x2c) * CDIM + c0];
                int tap = (dy + 1) * 3 + (dx + 1);
                float4 wt = *(const float4*)&cwT[tap * CDIM + c0];
                acc.x += v.x * wt.x;
                acc.y += v.y * wt.y;
                acc.z += v.z * wt.z;
                acc.w += v.w * wt.w;
            }
        }
        float4 sc = *(const float4*)&bnsc[c0];
        float4 bi = *(const float4*)&bnbi[c0];
        o.x = acc.x * sc.x + bi.x;
        o.y = acc.y * sc.y + bi.y;
        o.z = acc.z * sc.z + bi.z;
        o.w = acc.w * sc.w + bi.w;
        *(float4*)&x2[(size_t)t * CDIM + c0] = o;
    }
    // LN2 stats (two-pass, butterfly gives sum to all lanes)
    float s = o.x + o.y + o.z + o.w;
    for (int off = 32; off; off >>= 1) s += __shfl_xor(s, off);
    float m = s * (1.0f / 192.0f);
    float d0 = o.x - m, d1 = o.y - m, d2 = o.z - m, d3 = o.w - m;
    float v2 = act ? (d0*d0 + d1*d1 + d2*d2 + d3*d3) : 0.0f;
    for (int off = 32; off; off >>= 1) v2 += __shfl_xor(v2, off);
    if (lane == 0) {
        mv[t] = m;
        mv[NTOKALL + t] = 1.0f / sqrtf(v2 * (1.0f / 192.0f) + LN_EPS);
    }
}

// --------------- k5: LN2 + FC1 + GELU + FC2 + residual (MFMA, LDS-staged A-frags)
// R3 structure (40KB LDS, 6 hidden chunks, nf-split FC2 @1:4 load:MFMA = 176us
// measured) + fast_gelu. R4 LUT (LDS gather) and R5 32KB/12-iter both regressed.
__global__ __launch_bounds__(256) void k5_mlp_mfma(
    const float* __restrict__ x2, const float* __restrict__ mv2,
    const float* __restrict__ g2, const float* __restrict__ b2,
    const unsigned short* __restrict__ w1sw, const float* __restrict__ fb1,
    const unsigned short* __restrict__ w2sw, const float* __restrict__ fb2,
    float* __restrict__ out)
{
    __shared__ unsigned short aFrag[24 * 512];   // [mf 4][kk 6][lane 64][8 bf16] = 24KB
    __shared__ unsigned short hsw[16 * 512];     // hidden chunk 64x128, A-frag layout
    const int tid = threadIdx.x;
    const int w = tid >> 6, L = tid & 63, quad = L >> 4, l15 = L & 15;
    const int m0 = blockIdx.x * 64;
    // ---- build LN2(x2) A-fragments into LDS (cooperative, 6 slots/thread)
#pragma unroll
    for (int rsl = 0; rsl < 6; ++rsl) {
        int s = tid + 256 * rsl;                 // 0..1535
        int mf = s / 384, rem = s - mf * 384;
        int kk = rem >> 6, La = rem & 63;
        int row = m0 + mf * 16 + (La & 15);
        int c0 = kk * 32 + (La >> 4) * 8;
        float mm = mv2[row], rs = mv2[NTOKALL + row];
        const float* xr = x2 + (size_t)row * CDIM + c0;
        float4 xv0 = *(const float4*)&xr[0], xv1 = *(const float4*)&xr[4];
        float4 gv0 = *(const float4*)&g2[c0], gv1 = *(const float4*)&g2[c0 + 4];
        float4 bv0 = *(const float4*)&b2[c0], bv1 = *(const float4*)&b2[c0 + 4];
        bf16x8 av;
        av[0] = (short)f2bf((xv0.x - mm) * rs * gv0.x + bv0.x);
        av[1] = (short)f2bf((xv0.y - mm) * rs * gv0.y + bv0.y);
        av[2] = (short)f2bf((xv0.z - mm) * rs * gv0.z + bv0.z);
        av[3] = (short)f2bf((xv0.w - mm) * rs * gv0.w + bv0.w);
        av[4] = (short)f2bf((xv1.x - mm) * rs * gv1.x + bv1.x);
        av[5] = (short)f2bf((xv1.y - mm) * rs * gv1.y + bv1.y);
        av[6] = (short)f2bf((xv1.z - mm) * rs * gv1.z + bv1.z);
        av[7] = (short)f2bf((xv1.w - mm) * rs * gv1.w + bv1.w);
        *(bf16x8*)&aFrag[(size_t)s * 8] = av;
    }
    __syncthreads();

    f32x4 acc2[4][3];    // [mf][nf]  cols = w*48 + nf*16 + l15
#pragma unroll
    for (int mf = 0; mf < 4; ++mf)
#pragma unroll
        for (int nf = 0; nf < 3; ++nf) acc2[mf][nf] = (f32x4){0.f, 0.f, 0.f, 0.f};
    const bf16x8* B1 = (const bf16x8*)w1sw;
    const bf16x8* B2 = (const bf16x8*)w2sw;

    for (int ch = 0; ch < 6; ++ch) {
        // ---- FC1: hidden cols [ch*128 + 32w, +32) for all 64 rows
        f32x4 acc1[4][2];
#pragma unroll
        for (int mf = 0; mf < 4; ++mf)
#pragma unroll
            for (int nf = 0; nf < 2; ++nf) acc1[mf][nf] = (f32x4){0.f, 0.f, 0.f, 0.f};
#pragma unroll
        for (int kk = 0; kk < 6; ++kk) {
            bf16x8 bfr0 = B1[(size_t)((ch * 8 + 2 * w + 0) * 6 + kk) * 64 + L];
            bf16x8 bfr1 = B1[(size_t)((ch * 8 + 2 * w + 1) * 6 + kk) * 64 + L];
#pragma unroll
            for (int mf = 0; mf < 4; ++mf) {
                bf16x8 av = *(const bf16x8*)&aFrag[(size_t)((mf * 6 + kk) * 64 + L) * 8];
                acc1[mf][0] = __builtin_amdgcn_mfma_f32_16x16x32_bf16(av, bfr0, acc1[mf][0], 0, 0, 0);
                acc1[mf][1] = __builtin_amdgcn_mfma_f32_16x16x32_bf16(av, bfr1, acc1[mf][1], 0, 0, 0);
            }
        }
        __syncthreads();   // prior FC2 reads of hsw complete
        // ---- GELU + store hidden in A-frag layout (k-subtile = w)
#pragma unroll
        for (int mf = 0; mf < 4; ++mf) {
#pragma unroll
            for (int nf = 0; nf < 2; ++nf) {
                float bias = fb1[ch * 128 + 32 * w + nf * 16 + l15];
                int hi16 = (((nf * 16 + l15) >> 3) & 3) << 4;
#pragma unroll
                for (int i = 0; i < 4; ++i) {
                    float h = acc1[mf][nf][i] + bias;
                    h = fast_gelu(h);
                    int Ls = (quad * 4 + i) | hi16;
                    hsw[(w * 4 + mf) * 512 + Ls * 8 + (L & 7)] = f2bf(h);
                }
            }
        }
        __syncthreads();
        // ---- FC2 partial (nf-split): acc2[mf][nf] over this chunk's 128 k
#pragma unroll
        for (int kk2 = 0; kk2 < 4; ++kk2) {
            bf16x8 a2[4];
#pragma unroll
            for (int mf = 0; mf < 4; ++mf)
                a2[mf] = *(const bf16x8*)&hsw[(size_t)((kk2 * 4 + mf) * 512) + (size_t)L * 8];
#pragma unroll
            for (int nf = 0; nf < 3; ++nf) {
                bf16x8 bfr = B2[(size_t)((w * 3 + nf) * 24 + ch * 4 + kk2) * 64 + L];
#pragma unroll
                for (int mf = 0; mf < 4; ++mf)
                    acc2[mf][nf] = __builtin_amdgcn_mfma_f32_16x16x32_bf16(a2[mf], bfr, acc2[mf][nf], 0, 0, 0);
            }
        }
    }
    // ---- epilogue: + fc2_b + residual(x2); wave w covers cols [48w, 48w+48)
    float fb2v[3];
#pragma unroll
    for (int nf = 0; nf < 3; ++nf) fb2v[nf] = fb2[w * 48 + nf * 16 + l15];
#pragma unroll
    for (int mf = 0; mf < 4; ++mf) {
#pragma unroll
        for (int i = 0; i < 4; ++i) {
            int row = m0 + mf * 16 + quad * 4 + i;
            const float* xr = x2 + (size_t)row * CDIM;
            float* orow = out + (size_t)row * CDIM;
#pragma unroll
            for (int nf = 0; nf < 3; ++nf) {
                int col = w * 48 + nf * 16 + l15;
                orow[col] = acc2[mf][nf][i] + fb2v[nf] + xr[col];
            }
        }
    }
}

// ------------------------------------------------------------------- launcher
extern "C" void kernel_launch(void* const* d_in, const int* in_sizes, int n_in,
                              void* d_out, int out_size, void* d_ws, size_t ws_size,
                              hipStream_t stream) {
    const float* x     = (const float*)d_in[0];
    const float* g1    = (const float*)d_in[1];
    const float* b1    = (const float*)d_in[2];
    const float* qkvw  = (const float*)d_in[3];
    const float* qkvb  = (const float*)d_in[4];
    const float* abias = (const float*)d_in[5];
    const float* projw = (const float*)d_in[6];
    const float* projb = (const float*)d_in[7];
    const float* convw = (const float*)d_in[8];
    const float* bng   = (const float*)d_in[9];
    const float* bnb   = (const float*)d_in[10];
    const float* bnm   = (const float*)d_in[11];
    const float* bnv   = (const float*)d_in[12];
    const float* g2    = (const float*)d_in[13];
    const float* b2    = (const float*)d_in[14];
    const float* fc1w  = (const float*)d_in[15];
    const float* fc1b  = (const float*)d_in[16];
    const float* fc2w  = (const float*)d_in[17];
    const float* fc2b  = (const float*)d_in[18];
    float* out = (float*)d_out;

    // ws layout (floats):
    //   [0, 19267584)            qkv bf16 chunk scratch (28.9MB used) / later x2 fp32 (77MB)
    //   [19267584, 19468288)     LN mean/rstd (LN1, then overwritten by LN2 stats in k4)
    //   [19468288, 19689472)     swizzled bf16 weights (884,736 B)
    //   [19689472, ...)          cwT (1728) + bnsc (192) + bnbi (192)
    float* wsf   = (float*)d_ws;
    unsigned short* qkvws = (unsigned short*)wsf;
    float* x2b   = wsf;
    float* mv    = wsf + 19267584;
    unsigned short* qkvw_sw = (unsigned short*)(wsf + 19468288);
    unsigned short* projw_sw = qkvw_sw + 110592;
    unsigned short* fc1_sw   = projw_sw + 36864;
    unsigned short* fc2_sw   = fc1_sw + 147456;
    float* cwT  = wsf + 19689472;
    float* bnsc = cwT + 1728;
    float* bnbi = bnsc + 192;

    kw_swz<<<(216 * 64 + 255) / 256, 256, 0, stream>>>(qkvw, qkvw_sw, CDIM, QKVN);
    kw_swz<<<(72  * 64 + 255) / 256, 256, 0, stream>>>(projw, projw_sw, CDIM, CDIM);
    kw_swz<<<(288 * 64 + 255) / 256, 256, 0, stream>>>(fc1w, fc1_sw, CDIM, HIDDEN);
    kw_swz<<<(288 * 64 + 255) / 256, 256, 0, stream>>>(fc2w, fc2_sw, HIDDEN, CDIM);
    k_prep_conv<<<7, 256, 0, stream>>>(convw, bng, bnb, bnm, bnv, cwT, bnsc, bnbi);

    k0_stats<<<NTOKALL / 4, 256, 0, stream>>>(x, mv);
    for (int chunk = 0; chunk < NCHUNK; ++chunk) {
        int wbase = chunk * CHUNKW;
        k1_qkv_mfma<<<dim3(CHUNKM / 64, 3), 256, 0, stream>>>(
            x, mv, g1, b1, qkvw_sw, qkvb, qkvws, wbase);
        k2_attn<<<CHUNKW * 3, 128, 0, stream>>>(qkvws, abias);
        k3_proj_mfma<<<dim3(CHUNKM / 64, 3), 256, 0, stream>>>(
            qkvws, x, projw_sw, projb, out, wbase);
    }
    k4_convln<<<NTOKALL / 4, 256, 0, stream>>>(out, cwT, bnsc, bnbi, x2b, mv);
    k5_mlp_mfma<<<NTOKALL / 64, 256, 0, stream>>>(
        x2b, mv, g2, b2, fc1_sw, fc1b, fc2_sw, fc2b, out);
}

// Round 7
// 852.404 us; speedup vs baseline: 1.0710x; 1.0053x over previous
//
#include <hip/hip_runtime.h>

// Problem constants
#define CDIM   192
#define NHEADS 6
#define KDIM   32
#define NTOK   49          // tokens per window (7x7)
#define NPIX   3136        // 56*56
#define NB     32
#define NWIN   2048        // 32 * 8 * 8
#define CHUNKW 512         // windows per chunk
#define NCHUNK 4
#define CHUNKM (CHUNKW*NTOK)   // 25088
#define QKVN   576
#define HIDDEN 768
#define LN_EPS 1e-5f
#define BN_EPS 1e-5f
#define WSTR   28224       // 3*6*49*32 bf16 elements per window in qkv scratch
#define NTOKALL 100352     // 32*3136

typedef __attribute__((ext_vector_type(8))) short bf16x8;   // 8 bf16 = 4 VGPRs
typedef __attribute__((ext_vector_type(4))) float f32x4;

__device__ __forceinline__ unsigned short f2bf(float f) {
    unsigned u = __float_as_uint(f);
    return (unsigned short)((u + 0x7FFFu + ((u >> 16) & 1u)) >> 16);   // RNE
}
__device__ __forceinline__ float bf2f(unsigned short s) {
    return __uint_as_float(((unsigned)s) << 16);
}

// Fast exact-GELU: 0.5*x*(1+erf(x/sqrt(2))) with Abramowitz-Stegun 7.1.26 erf
// (|erf err| <= 1.5e-7; validated in R1). ~10 full-rate FMA + 2 trans ops.
__device__ __forceinline__ float fast_gelu(float x) {
    float ax = fabsf(x);
    float t  = __builtin_amdgcn_rcpf(fmaf(0.23164190f, ax, 1.0f)); // 1/(1+p*ax/sqrt2)
    float p  = fmaf(t, 1.061405429f, -1.453152027f);
    p = fmaf(t, p, 1.421413741f);
    p = fmaf(t, p, -0.284496736f);
    p = fmaf(t, p, 0.254829592f);
    p = p * t;
    float e  = __expf(-0.5f * x * x);
    float q  = ax * p * e;
    return 0.5f * (x + ax - q);              // branch-free both signs
}

// ------------------------------------------- weight swizzle: fp32 KxN -> bf16 frags
// frag layout: subtile id = (n0/16)*(K/32) + (k0/32); lane L holds
// W[k0 + (L>>4)*8 + j][n0 + (L&15)], j=0..7, stored as 16B per lane.
__global__ void kw_swz(const float* __restrict__ W, unsigned short* __restrict__ o,
                       int K, int N) {
    int t = blockIdx.x * 256 + threadIdx.x;
    int lane = t & 63, sub = t >> 6;
    int ksub = K >> 5;
    int total = (N >> 4) * ksub;
    if (sub >= total) return;
    int nfr = sub / ksub, kk = sub - nfr * ksub;
    int n = nfr * 16 + (lane & 15);
    int kb = kk * 32 + (lane >> 4) * 8;
    unsigned p0 = (unsigned)f2bf(W[(size_t)(kb + 0) * N + n]) |
                  ((unsigned)f2bf(W[(size_t)(kb + 1) * N + n]) << 16);
    unsigned p1 = (unsigned)f2bf(W[(size_t)(kb + 2) * N + n]) |
                  ((unsigned)f2bf(W[(size_t)(kb + 3) * N + n]) << 16);
    unsigned p2 = (unsigned)f2bf(W[(size_t)(kb + 4) * N + n]) |
                  ((unsigned)f2bf(W[(size_t)(kb + 5) * N + n]) << 16);
    unsigned p3 = (unsigned)f2bf(W[(size_t)(kb + 6) * N + n]) |
                  ((unsigned)f2bf(W[(size_t)(kb + 7) * N + n]) << 16);
    uint4 v = {p0, p1, p2, p3};
    *(uint4*)(o + (size_t)(sub * 64 + lane) * 8) = v;
}

// ------------------------- conv/BN prep: cw [C][9] -> cwT [9][C]; fold BN scale/bias
__global__ void k_prep_conv(const float* __restrict__ cw,
    const float* __restrict__ bg, const float* __restrict__ bb,
    const float* __restrict__ bm, const float* __restrict__ bv,
    float* __restrict__ cwT, float* __restrict__ bnsc, float* __restrict__ bnbi)
{
    int t = threadIdx.x + blockIdx.x * 256;
    if (t < 9 * CDIM) {
        int tap = t / CDIM, c = t - tap * CDIM;
        cwT[t] = cw[c * 9 + tap];
    }
    if (t < CDIM) {
        float s = bg[t] * rsqrtf(bv[t] + BN_EPS);
        bnsc[t] = s;
        bnbi[t] = bb[t] - bm[t] * s;
    }
}

// ---------------------------------------------------------------- k0: LN1 stats
__global__ void k0_stats(const float* __restrict__ x, float* __restrict__ mv) {
    int t    = blockIdx.x * 4 + (threadIdx.x >> 6);
    int lane = threadIdx.x & 63;
    const float* row = x + (size_t)t * CDIM;
    float e0 = row[lane], e1 = row[lane + 64], e2 = row[lane + 128];
    float s = e0 + e1 + e2;
    for (int o = 32; o; o >>= 1) s += __shfl_xor(s, o);
    float m = s * (1.0f / 192.0f);
    float d0 = e0 - m, d1 = e1 - m, d2 = e2 - m;
    float v = d0*d0 + d1*d1 + d2*d2;
    for (int o = 32; o; o >>= 1) v += __shfl_xor(v, o);
    if (lane == 0) {
        mv[t] = m;
        mv[NTOKALL + t] = 1.0f / sqrtf(v * (1.0f / 192.0f) + LN_EPS);
    }
}

// ------------------------------------------------- k1: LN1 + QKV GEMM (MFMA bf16)
__global__ __launch_bounds__(256) void k1_qkv_mfma(
    const float* __restrict__ x,  const float* __restrict__ mv,
    const float* __restrict__ g1, const float* __restrict__ b1,
    const unsigned short* __restrict__ wsw, const float* __restrict__ qb,
    unsigned short* __restrict__ qkv, int wbase)
{
    const int tid = threadIdx.x;
    const int w = tid >> 6, L = tid & 63, quad = L >> 4, l15 = L & 15;
    const int m0 = blockIdx.x * 64;
    const int Nt = blockIdx.y;                 // 0..2
    int mA = m0 + w * 16 + l15;
    int gt = wbase * NTOK + mA;
    int wg = gt / 49, tok = gt - wg * 49;
    int bb = wg >> 6, wrem = wg & 63;
    int rr = tok / 7, cc = tok - rr * 7;
    int xrow = bb * NPIX + ((wrem >> 3) * 7 + rr) * 56 + (wrem & 7) * 7 + cc;
    float mean = mv[xrow], rstd = mv[NTOKALL + xrow];
    const float* xr = x + (size_t)xrow * CDIM;
    bf16x8 a[6];
#pragma unroll
    for (int kk = 0; kk < 6; ++kk) {
        int c0 = kk * 32 + quad * 8;
        float4 xv0 = *(const float4*)&xr[c0], xv1 = *(const float4*)&xr[c0 + 4];
        float4 gv0 = *(const float4*)&g1[c0], gv1 = *(const float4*)&g1[c0 + 4];
        float4 bv0 = *(const float4*)&b1[c0], bv1 = *(const float4*)&b1[c0 + 4];
        bf16x8 av;
        av[0] = (short)f2bf((xv0.x - mean) * rstd * gv0.x + bv0.x);
        av[1] = (short)f2bf((xv0.y - mean) * rstd * gv0.y + bv0.y);
        av[2] = (short)f2bf((xv0.z - mean) * rstd * gv0.z + bv0.z);
        av[3] = (short)f2bf((xv0.w - mean) * rstd * gv0.w + bv0.w);
        av[4] = (short)f2bf((xv1.x - mean) * rstd * gv1.x + bv1.x);
        av[5] = (short)f2bf((xv1.y - mean) * rstd * gv1.y + bv1.y);
        av[6] = (short)f2bf((xv1.z - mean) * rstd * gv1.z + bv1.z);
        av[7] = (short)f2bf((xv1.w - mean) * rstd * gv1.w + bv1.w);
        a[kk] = av;
    }
    f32x4 acc[12];
#pragma unroll
    for (int nf = 0; nf < 12; ++nf) acc[nf] = (f32x4){0.f, 0.f, 0.f, 0.f};
    const bf16x8* B = (const bf16x8*)wsw;
#pragma unroll
    for (int kk = 0; kk < 6; ++kk) {
#pragma unroll
        for (int nf = 0; nf < 12; ++nf) {
            bf16x8 bfr = B[(size_t)((Nt * 12 + nf) * 6 + kk) * 64 + L];
            acc[nf] = __builtin_amdgcn_mfma_f32_16x16x32_bf16(a[kk], bfr, acc[nf], 0, 0, 0);
        }
    }
    float qbv[12];
#pragma unroll
    for (int nf = 0; nf < 12; ++nf) qbv[nf] = qb[Nt * 192 + nf * 16 + l15];
#pragma unroll
    for (int i = 0; i < 4; ++i) {
        int mrow = m0 + w * 16 + quad * 4 + i;
        int wrel = mrow / 49, tokr = mrow - wrel * 49;
        unsigned short* obase = qkv + (size_t)wrel * WSTR + tokr * 32;
#pragma unroll
        for (int nf = 0; nf < 12; ++nf) {
            int n = Nt * 192 + nf * 16 + l15;
            int h = n / 96, rem = n - h * 96;
            int part = rem >> 5, d = rem & 31;
            obase[(size_t)(part * 6 + h) * 1568 + d] = f2bf(acc[nf][i] + qbv[nf]);
        }
    }
}

// ----------------------------------------------- k2: windowed attention (head pair)
__global__ __launch_bounds__(128) void k2_attn(
    unsigned short* __restrict__ qkv, const float* __restrict__ abias)
{
    __shared__ float kv[6272];   // [kv part(2)][h(2)][tok 49][d 32], f32
    const int wrel = blockIdx.x / 3;
    const int pair = blockIdx.x - wrel * 3;
    const int h0 = pair * 2;
    unsigned short* base = qkv + (size_t)wrel * WSTR;
    for (int idx = threadIdx.x; idx < 784; idx += 128) {   // 8 elems each
        int part = idx / 392;
        int rem  = idx - part * 392;
        int h    = rem / 196;
        int off8 = rem - h * 196;
        bf16x8 v = *(const bf16x8*)&base[(size_t)((part + 1) * 6 + h0 + h) * 1568 + off8 * 8];
        float* dst = &kv[((part * 2 + h) * 196 + off8) * 8];
        float4 f0 = {bf2f((unsigned short)v[0]), bf2f((unsigned short)v[1]),
                     bf2f((unsigned short)v[2]), bf2f((unsigned short)v[3])};
        float4 f1 = {bf2f((unsigned short)v[4]), bf2f((unsigned short)v[5]),
                     bf2f((unsigned short)v[6]), bf2f((unsigned short)v[7])};
        *(float4*)&dst[0] = f0;
        *(float4*)&dst[4] = f1;
    }
    __syncthreads();
    const int item = threadIdx.x;
    if (item >= 98) return;
    const int h = item / 49;
    const int row = item - h * 49;
    const int hg = h0 + h;
    unsigned short* qptr = base + (size_t)hg * 1568 + row * 32;
    float4 q4[8];
#pragma unroll
    for (int dq2 = 0; dq2 < 4; ++dq2) {
        bf16x8 v = *(const bf16x8*)&qptr[dq2 * 8];
        q4[dq2 * 2]     = (float4){bf2f((unsigned short)v[0]), bf2f((unsigned short)v[1]),
                                   bf2f((unsigned short)v[2]), bf2f((unsigned short)v[3])};
        q4[dq2 * 2 + 1] = (float4){bf2f((unsigned short)v[4]), bf2f((unsigned short)v[5]),
                                   bf2f((unsigned short)v[6]), bf2f((unsigned short)v[7])};
    }
    const int rr = row / 7, rc = row - rr * 7;
    const float scale = 0.17677669529663687f;   // 32^-0.5
    const float* kbase = &kv[(h * 49) * 32];
    const float* vbase = &kv[(98 + h * 49) * 32];
    float s[49];
    for (int j = 0; j < 49; ++j) {
        const float* kr = kbase + j * 32;
        float4 a = {0, 0, 0, 0};
#pragma unroll
        for (int dq = 0; dq < 8; ++dq) {
            float4 k4 = *(const float4*)&kr[dq * 4];
            a.x += q4[dq].x * k4.x; a.y += q4[dq].y * k4.y;
            a.z += q4[dq].z * k4.z; a.w += q4[dq].w * k4.w;
        }
        int jr = j / 7, jc = j - jr * 7;
        int dy = rr > jr ? rr - jr : jr - rr;
        int dx = rc > jc ? rc - jc : jc - rc;
        s[j] = (a.x + a.y + a.z + a.w) * scale + abias[hg * 49 + dy * 7 + dx];
    }
    float mx = s[0];
    for (int j = 1; j < 49; ++j) mx = fmaxf(mx, s[j]);
    float sum = 0.0f;
    for (int j = 0; j < 49; ++j) { s[j] = __expf(s[j] - mx); sum += s[j]; }
    float rinv = 1.0f / sum;
    float4 o[8] = {};
    for (int j = 0; j < 49; ++j) {
        float p = s[j];
        const float* vr = vbase + j * 32;
#pragma unroll
        for (int dq = 0; dq < 8; ++dq) {
            float4 v4 = *(const float4*)&vr[dq * 4];
            o[dq].x += p * v4.x; o[dq].y += p * v4.y;
            o[dq].z += p * v4.z; o[dq].w += p * v4.w;
        }
    }
#pragma unroll
    for (int dq = 0; dq < 8; ++dq) {
        uint2 pk;
        pk.x = (unsigned)f2bf(o[dq].x * rinv) | ((unsigned)f2bf(o[dq].y * rinv) << 16);
        pk.y = (unsigned)f2bf(o[dq].z * rinv) | ((unsigned)f2bf(o[dq].w * rinv) << 16);
        *(uint2*)&qptr[dq * 4] = pk;       // overwrite q slot (own row only)
    }
}

// --------------------------- k3: proj GEMM (MFMA) + bias + residual + window reverse
__global__ __launch_bounds__(256) void k3_proj_mfma(
    const unsigned short* __restrict__ qkv, const float* __restrict__ x,
    const unsigned short* __restrict__ wsw, const float* __restrict__ pb,
    float* __restrict__ x1, int wbase)
{
    const int tid = threadIdx.x;
    const int w = tid >> 6, L = tid & 63, quad = L >> 4, l15 = L & 15;
    const int m0 = blockIdx.x * 64;
    const int Nt = blockIdx.y;                 // 0..2, 64 cols each
    int mA = m0 + w * 16 + l15;
    int wrelA = mA / 49, tokA = mA - wrelA * 49;
    const unsigned short* ar = qkv + (size_t)wrelA * WSTR + tokA * 32 + quad * 8;
    bf16x8 a[6];
#pragma unroll
    for (int kk = 0; kk < 6; ++kk)             // head = kk
        a[kk] = *(const bf16x8*)&ar[(size_t)kk * 1568];
    f32x4 acc[4];
#pragma unroll
    for (int nf = 0; nf < 4; ++nf) acc[nf] = (f32x4){0.f, 0.f, 0.f, 0.f};
    const bf16x8* B = (const bf16x8*)wsw;
#pragma unroll
    for (int kk = 0; kk < 6; ++kk) {
#pragma unroll
        for (int nf = 0; nf < 4; ++nf) {
            bf16x8 bfr = B[(size_t)((Nt * 4 + nf) * 6 + kk) * 64 + L];
            acc[nf] = __builtin_amdgcn_mfma_f32_16x16x32_bf16(a[kk], bfr, acc[nf], 0, 0, 0);
        }
    }
    float pbv[4];
#pragma unroll
    for (int nf = 0; nf < 4; ++nf) pbv[nf] = pb[Nt * 64 + nf * 16 + l15];
#pragma unroll
    for (int i = 0; i < 4; ++i) {
        int mrow = m0 + w * 16 + quad * 4 + i;
        int wrel = mrow / 49, tokr = mrow - wrel * 49;
        int wg = wbase + wrel;
        int bb = wg >> 6, wrem = wg & 63;
        int r = tokr / 7, c = tokr - r * 7;
        size_t xoff = ((size_t)(bb * NPIX + ((wrem >> 3) * 7 + r) * 56 + (wrem & 7) * 7 + c)) * CDIM;
#pragma unroll
        for (int nf = 0; nf < 4; ++nf) {
            int col = Nt * 64 + nf * 16 + l15;
            x1[xoff + col] = acc[nf][i] + pbv[nf] + x[xoff + col];
        }
    }
}

// ---------------------- k4: depthwise conv3x3 + BN + LN2 stats (1 wave per token)
// XCD-bijective block swizzle (T1): 25088 blocks = 8 * 3136 exactly, so
// sbid = (bid%8)*3136 + bid/8 gives each XCD a contiguous 4-image band.
// Without it, adjacent tokens (sharing 6/9 halo rows) land on different XCDs
// whose L2s aren't shared -> R2 profile showed 163MB HBM fetch vs 77MB ideal.
__global__ __launch_bounds__(256) void k4_convln(
    const float* __restrict__ x1, const float* __restrict__ cwT,
    const float* __restrict__ bnsc, const float* __restrict__ bnbi,
    float* __restrict__ x2, float* __restrict__ mv)
{
    const int w = threadIdx.x >> 6, lane = threadIdx.x & 63;
    const int bid = blockIdx.x;
    const int sbid = (bid & 7) * 3136 + (bid >> 3);   // bijective: 25088 = 8*3136
    const int t = sbid * 4 + w;
    const int b = t / NPIX, l = t - b * NPIX;
    const int yy = l / 56, xx = l - yy * 56;
    const bool act = lane < 48;
    const int c0 = lane * 4;
    float4 o = {0, 0, 0, 0};
    if (act) {
        const float* xb = x1 + (size_t)b * NPIX * CDIM;
        float4 acc = {0, 0, 0, 0};
#pragma unroll
        for (int dy = -1; dy <= 1; ++dy) {
            int y2 = yy + dy;
            if ((unsigned)y2 >= 56u) continue;
#pragma unroll
            for (int dx = -1; dx <= 1; ++dx) {
                int x2c = xx + dx;
                if ((unsigned)x2c >= 56u) continue;
                float4 v = *(const float4*)&xb[(size_t)(y2 * 56 + x2c) * CDIM + c0];
                int tap = (dy + 1) * 3 + (dx + 1);
                float4 wt = *(const float4*)&cwT[tap * CDIM + c0];
                acc.x += v.x * wt.x;
                acc.y += v.y * wt.y;
                acc.z += v.z * wt.z;
                acc.w += v.w * wt.w;
            }
        }
        float4 sc = *(const float4*)&bnsc[c0];
        float4 bi = *(const float4*)&bnbi[c0];
        o.x = acc.x * sc.x + bi.x;
        o.y = acc.y * sc.y + bi.y;
        o.z = acc.z * sc.z + bi.z;
        o.w = acc.w * sc.w + bi.w;
        *(float4*)&x2[(size_t)t * CDIM + c0] = o;
    }
    // LN2 stats (two-pass, butterfly gives sum to all lanes)
    float s = o.x + o.y + o.z + o.w;
    for (int off = 32; off; off >>= 1) s += __shfl_xor(s, off);
    float m = s * (1.0f / 192.0f);
    float d0 = o.x - m, d1 = o.y - m, d2 = o.z - m, d3 = o.w - m;
    float v2 = act ? (d0*d0 + d1*d1 + d2*d2 + d3*d3) : 0.0f;
    for (int off = 32; off; off >>= 1) v2 += __shfl_xor(v2, off);
    if (lane == 0) {
        mv[t] = m;
        mv[NTOKALL + t] = 1.0f / sqrtf(v2 * (1.0f / 192.0f) + LN_EPS);
    }
}

// --------------- k5: LN2 + FC1 + GELU + FC2 + residual (MFMA, LDS-staged A-frags)
// R3 structure (40KB LDS, 6 hidden chunks, nf-split FC2 @1:4 load:MFMA) +
// fast_gelu (R6: k5 176->168us, VALUBusy 57->37%).
__global__ __launch_bounds__(256) void k5_mlp_mfma(
    const float* __restrict__ x2, const float* __restrict__ mv2,
    const float* __restrict__ g2, const float* __restrict__ b2,
    const unsigned short* __restrict__ w1sw, const float* __restrict__ fb1,
    const unsigned short* __restrict__ w2sw, const float* __restrict__ fb2,
    float* __restrict__ out)
{
    __shared__ unsigned short aFrag[24 * 512];   // [mf 4][kk 6][lane 64][8 bf16] = 24KB
    __shared__ unsigned short hsw[16 * 512];     // hidden chunk 64x128, A-frag layout
    const int tid = threadIdx.x;
    const int w = tid >> 6, L = tid & 63, quad = L >> 4, l15 = L & 15;
    const int m0 = blockIdx.x * 64;
    // ---- build LN2(x2) A-fragments into LDS (cooperative, 6 slots/thread)
#pragma unroll
    for (int rsl = 0; rsl < 6; ++rsl) {
        int s = tid + 256 * rsl;                 // 0..1535
        int mf = s / 384, rem = s - mf * 384;
        int kk = rem >> 6, La = rem & 63;
        int row = m0 + mf * 16 + (La & 15);
        int c0 = kk * 32 + (La >> 4) * 8;
        float mm = mv2[row], rs = mv2[NTOKALL + row];
        const float* xr = x2 + (size_t)row * CDIM + c0;
        float4 xv0 = *(const float4*)&xr[0], xv1 = *(const float4*)&xr[4];
        float4 gv0 = *(const float4*)&g2[c0], gv1 = *(const float4*)&g2[c0 + 4];
        float4 bv0 = *(const float4*)&b2[c0], bv1 = *(const float4*)&b2[c0 + 4];
        bf16x8 av;
        av[0] = (short)f2bf((xv0.x - mm) * rs * gv0.x + bv0.x);
        av[1] = (short)f2bf((xv0.y - mm) * rs * gv0.y + bv0.y);
        av[2] = (short)f2bf((xv0.z - mm) * rs * gv0.z + bv0.z);
        av[3] = (short)f2bf((xv0.w - mm) * rs * gv0.w + bv0.w);
        av[4] = (short)f2bf((xv1.x - mm) * rs * gv1.x + bv1.x);
        av[5] = (short)f2bf((xv1.y - mm) * rs * gv1.y + bv1.y);
        av[6] = (short)f2bf((xv1.z - mm) * rs * gv1.z + bv1.z);
        av[7] = (short)f2bf((xv1.w - mm) * rs * gv1.w + bv1.w);
        *(bf16x8*)&aFrag[(size_t)s * 8] = av;
    }
    __syncthreads();

    f32x4 acc2[4][3];    // [mf][nf]  cols = w*48 + nf*16 + l15
#pragma unroll
    for (int mf = 0; mf < 4; ++mf)
#pragma unroll
        for (int nf = 0; nf < 3; ++nf) acc2[mf][nf] = (f32x4){0.f, 0.f, 0.f, 0.f};
    const bf16x8* B1 = (const bf16x8*)w1sw;
    const bf16x8* B2 = (const bf16x8*)w2sw;

    for (int ch = 0; ch < 6; ++ch) {
        // ---- FC1: hidden cols [ch*128 + 32w, +32) for all 64 rows
        f32x4 acc1[4][2];
#pragma unroll
        for (int mf = 0; mf < 4; ++mf)
#pragma unroll
            for (int nf = 0; nf < 2; ++nf) acc1[mf][nf] = (f32x4){0.f, 0.f, 0.f, 0.f};
#pragma unroll
        for (int kk = 0; kk < 6; ++kk) {
            bf16x8 bfr0 = B1[(size_t)((ch * 8 + 2 * w + 0) * 6 + kk) * 64 + L];
            bf16x8 bfr1 = B1[(size_t)((ch * 8 + 2 * w + 1) * 6 + kk) * 64 + L];
#pragma unroll
            for (int mf = 0; mf < 4; ++mf) {
                bf16x8 av = *(const bf16x8*)&aFrag[(size_t)((mf * 6 + kk) * 64 + L) * 8];
                acc1[mf][0] = __builtin_amdgcn_mfma_f32_16x16x32_bf16(av, bfr0, acc1[mf][0], 0, 0, 0);
                acc1[mf][1] = __builtin_amdgcn_mfma_f32_16x16x32_bf16(av, bfr1, acc1[mf][1], 0, 0, 0);
            }
        }
        __syncthreads();   // prior FC2 reads of hsw complete
        // ---- GELU + store hidden in A-frag layout (k-subtile = w)
#pragma unroll
        for (int mf = 0; mf < 4; ++mf) {
#pragma unroll
            for (int nf = 0; nf < 2; ++nf) {
                float bias = fb1[ch * 128 + 32 * w + nf * 16 + l15];
                int hi16 = (((nf * 16 + l15) >> 3) & 3) << 4;
#pragma unroll
                for (int i = 0; i < 4; ++i) {
                    float h = acc1[mf][nf][i] + bias;
                    h = fast_gelu(h);
                    int Ls = (quad * 4 + i) | hi16;
                    hsw[(w * 4 + mf) * 512 + Ls * 8 + (L & 7)] = f2bf(h);
                }
            }
        }
        __syncthreads();
        // ---- FC2 partial (nf-split): acc2[mf][nf] over this chunk's 128 k
#pragma unroll
        for (int kk2 = 0; kk2 < 4; ++kk2) {
            bf16x8 a2[4];
#pragma unroll
            for (int mf = 0; mf < 4; ++mf)
                a2[mf] = *(const bf16x8*)&hsw[(size_t)((kk2 * 4 + mf) * 512) + (size_t)L * 8];
#pragma unroll
            for (int nf = 0; nf < 3; ++nf) {
                bf16x8 bfr = B2[(size_t)((w * 3 + nf) * 24 + ch * 4 + kk2) * 64 + L];
#pragma unroll
                for (int mf = 0; mf < 4; ++mf)
                    acc2[mf][nf] = __builtin_amdgcn_mfma_f32_16x16x32_bf16(a2[mf], bfr, acc2[mf][nf], 0, 0, 0);
            }
        }
    }
    // ---- epilogue: + fc2_b + residual(x2); wave w covers cols [48w, 48w+48)
    float fb2v[3];
#pragma unroll
    for (int nf = 0; nf < 3; ++nf) fb2v[nf] = fb2[w * 48 + nf * 16 + l15];
#pragma unroll
    for (int mf = 0; mf < 4; ++mf) {
#pragma unroll
        for (int i = 0; i < 4; ++i) {
            int row = m0 + mf * 16 + quad * 4 + i;
            const float* xr = x2 + (size_t)row * CDIM;
            float* orow = out + (size_t)row * CDIM;
#pragma unroll
            for (int nf = 0; nf < 3; ++nf) {
                int col = w * 48 + nf * 16 + l15;
                orow[col] = acc2[mf][nf][i] + fb2v[nf] + xr[col];
            }
        }
    }
}

// ------------------------------------------------------------------- launcher
extern "C" void kernel_launch(void* const* d_in, const int* in_sizes, int n_in,
                              void* d_out, int out_size, void* d_ws, size_t ws_size,
                              hipStream_t stream) {
    const float* x     = (const float*)d_in[0];
    const float* g1    = (const float*)d_in[1];
    const float* b1    = (const float*)d_in[2];
    const float* qkvw  = (const float*)d_in[3];
    const float* qkvb  = (const float*)d_in[4];
    const float* abias = (const float*)d_in[5];
    const float* projw = (const float*)d_in[6];
    const float* projb = (const float*)d_in[7];
    const float* convw = (const float*)d_in[8];
    const float* bng   = (const float*)d_in[9];
    const float* bnb   = (const float*)d_in[10];
    const float* bnm   = (const float*)d_in[11];
    const float* bnv   = (const float*)d_in[12];
    const float* g2    = (const float*)d_in[13];
    const float* b2    = (const float*)d_in[14];
    const float* fc1w  = (const float*)d_in[15];
    const float* fc1b  = (const float*)d_in[16];
    const float* fc2w  = (const float*)d_in[17];
    const float* fc2b  = (const float*)d_in[18];
    float* out = (float*)d_out;

    // ws layout (floats):
    //   [0, 19267584)            qkv bf16 chunk scratch (28.9MB used) / later x2 fp32 (77MB)
    //   [19267584, 19468288)     LN mean/rstd (LN1, then overwritten by LN2 stats in k4)
    //   [19468288, 19689472)     swizzled bf16 weights (884,736 B)
    //   [19689472, ...)          cwT (1728) + bnsc (192) + bnbi (192)
    float* wsf   = (float*)d_ws;
    unsigned short* qkvws = (unsigned short*)wsf;
    float* x2b   = wsf;
    float* mv    = wsf + 19267584;
    unsigned short* qkvw_sw = (unsigned short*)(wsf + 19468288);
    unsigned short* projw_sw = qkvw_sw + 110592;
    unsigned short* fc1_sw   = projw_sw + 36864;
    unsigned short* fc2_sw   = fc1_sw + 147456;
    float* cwT  = wsf + 19689472;
    float* bnsc = cwT + 1728;
    float* bnbi = bnsc + 192;

    kw_swz<<<(216 * 64 + 255) / 256, 256, 0, stream>>>(qkvw, qkvw_sw, CDIM, QKVN);
    kw_swz<<<(72  * 64 + 255) / 256, 256, 0, stream>>>(projw, projw_sw, CDIM, CDIM);
    kw_swz<<<(288 * 64 + 255) / 256, 256, 0, stream>>>(fc1w, fc1_sw, CDIM, HIDDEN);
    kw_swz<<<(288 * 64 + 255) / 256, 256, 0, stream>>>(fc2w, fc2_sw, HIDDEN, CDIM);
    k_prep_conv<<<7, 256, 0, stream>>>(convw, bng, bnb, bnm, bnv, cwT, bnsc, bnbi);

    k0_stats<<<NTOKALL / 4, 256, 0, stream>>>(x, mv);
    for (int chunk = 0; chunk < NCHUNK; ++chunk) {
        int wbase = chunk * CHUNKW;
        k1_qkv_mfma<<<dim3(CHUNKM / 64, 3), 256, 0, stream>>>(
            x, mv, g1, b1, qkvw_sw, qkvb, qkvws, wbase);
        k2_attn<<<CHUNKW * 3, 128, 0, stream>>>(qkvws, abias);
        k3_proj_mfma<<<dim3(CHUNKM / 64, 3), 256, 0, stream>>>(
            qkvws, x, projw_sw, projb, out, wbase);
    }
    k4_convln<<<NTOKALL / 4, 256, 0, stream>>>(out, cwT, bnsc, bnbi, x2b, mv);
    k5_mlp_mfma<<<NTOKALL / 64, 256, 0, stream>>>(
        x2b, mv, g2, b2, fc1_sw, fc1b, fc2_sw, fc2b, out);
}

// Round 9
// 725.882 us; speedup vs baseline: 1.2576x; 1.1743x over previous
//
#include <hip/hip_runtime.h>

// Problem constants
#define CDIM   192
#define NHEADS 6
#define KDIM   32
#define NTOK   49          // tokens per window (7x7)
#define NPIX   3136        // 56*56
#define NB     32
#define NWIN   2048        // 32 * 8 * 8
#define QKVN   576
#define HIDDEN 768
#define LN_EPS 1e-5f
#define BN_EPS 1e-5f
#define WSTR   28224       // 3*6*49*32 bf16 elements per window in qkv scratch
#define NTOKALL 100352     // 32*3136

typedef __attribute__((ext_vector_type(8))) short bf16x8;   // 8 bf16 = 4 VGPRs
typedef __attribute__((ext_vector_type(4))) float f32x4;

__device__ __forceinline__ unsigned short f2bf(float f) {
    unsigned u = __float_as_uint(f);
    return (unsigned short)((u + 0x7FFFu + ((u >> 16) & 1u)) >> 16);   // RNE
}
__device__ __forceinline__ float bf2f(unsigned short s) {
    return __uint_as_float(((unsigned)s) << 16);
}

// Fast exact-GELU: 0.5*x*(1+erf(x/sqrt(2))) with Abramowitz-Stegun 7.1.26 erf
// (|erf err| <= 1.5e-7; validated in R1). ~10 full-rate FMA + 2 trans ops.
__device__ __forceinline__ float fast_gelu(float x) {
    float ax = fabsf(x);
    float t  = __builtin_amdgcn_rcpf(fmaf(0.23164190f, ax, 1.0f)); // 1/(1+p*ax/sqrt2)
    float p  = fmaf(t, 1.061405429f, -1.453152027f);
    p = fmaf(t, p, 1.421413741f);
    p = fmaf(t, p, -0.284496736f);
    p = fmaf(t, p, 0.254829592f);
    p = p * t;
    float e  = __expf(-0.5f * x * x);
    float q  = ax * p * e;
    return 0.5f * (x + ax - q);              // branch-free both signs
}

// ------------------------------------------- weight swizzle: fp32 KxN -> bf16 frags
// frag layout: subtile id = (n0/16)*(K/32) + (k0/32); lane L holds
// W[k0 + (L>>4)*8 + j][n0 + (L&15)], j=0..7, stored as 16B per lane.
__global__ void kw_swz(const float* __restrict__ W, unsigned short* __restrict__ o,
                       int K, int N) {
    int t = blockIdx.x * 256 + threadIdx.x;
    int lane = t & 63, sub = t >> 6;
    int ksub = K >> 5;
    int total = (N >> 4) * ksub;
    if (sub >= total) return;
    int nfr = sub / ksub, kk = sub - nfr * ksub;
    int n = nfr * 16 + (lane & 15);
    int kb = kk * 32 + (lane >> 4) * 8;
    unsigned p0 = (unsigned)f2bf(W[(size_t)(kb + 0) * N + n]) |
                  ((unsigned)f2bf(W[(size_t)(kb + 1) * N + n]) << 16);
    unsigned p1 = (unsigned)f2bf(W[(size_t)(kb + 2) * N + n]) |
                  ((unsigned)f2bf(W[(size_t)(kb + 3) * N + n]) << 16);
    unsigned p2 = (unsigned)f2bf(W[(size_t)(kb + 4) * N + n]) |
                  ((unsigned)f2bf(W[(size_t)(kb + 5) * N + n]) << 16);
    unsigned p3 = (unsigned)f2bf(W[(size_t)(kb + 6) * N + n]) |
                  ((unsigned)f2bf(W[(size_t)(kb + 7) * N + n]) << 16);
    uint4 v = {p0, p1, p2, p3};
    *(uint4*)(o + (size_t)(sub * 64 + lane) * 8) = v;
}

// ------------------------- conv/BN prep: cw [C][9] -> cwT [9][C]; fold BN scale/bias
__global__ void k_prep_conv(const float* __restrict__ cw,
    const float* __restrict__ bg, const float* __restrict__ bb,
    const float* __restrict__ bm, const float* __restrict__ bv,
    float* __restrict__ cwT, float* __restrict__ bnsc, float* __restrict__ bnbi)
{
    int t = threadIdx.x + blockIdx.x * 256;
    if (t < 9 * CDIM) {
        int tap = t / CDIM, c = t - tap * CDIM;
        cwT[t] = cw[c * 9 + tap];
    }
    if (t < CDIM) {
        float s = bg[t] * rsqrtf(bv[t] + BN_EPS);
        bnsc[t] = s;
        bnbi[t] = bb[t] - bm[t] * s;
    }
}

// ---------------------------------------------------------------- k0: LN1 stats
__global__ void k0_stats(const float* __restrict__ x, float* __restrict__ mv) {
    int t    = blockIdx.x * 4 + (threadIdx.x >> 6);
    int lane = threadIdx.x & 63;
    const float* row = x + (size_t)t * CDIM;
    float e0 = row[lane], e1 = row[lane + 64], e2 = row[lane + 128];
    float s = e0 + e1 + e2;
    for (int o = 32; o; o >>= 1) s += __shfl_xor(s, o);
    float m = s * (1.0f / 192.0f);
    float d0 = e0 - m, d1 = e1 - m, d2 = e2 - m;
    float v = d0*d0 + d1*d1 + d2*d2;
    for (int o = 32; o; o >>= 1) v += __shfl_xor(v, o);
    if (lane == 0) {
        mv[t] = m;
        mv[NTOKALL + t] = 1.0f / sqrtf(v * (1.0f / 192.0f) + LN_EPS);
    }
}

// ------------------------------------------------- k1: LN1 + QKV GEMM (MFMA bf16)
// 1D grid + bijective XCD swizzle; the 3 Nt-siblings of one m-tile (which load
// IDENTICAL A-fragments/x-rows) land in the same XCD's contiguous band ->
// x is fetched ~1x instead of 3x across non-coherent L2s.
__global__ __launch_bounds__(256) void k1_qkv_mfma(
    const float* __restrict__ x,  const float* __restrict__ mv,
    const float* __restrict__ g1, const float* __restrict__ b1,
    const unsigned short* __restrict__ wsw, const float* __restrict__ qb,
    unsigned short* __restrict__ qkv, int wbase)
{
    const int tid = threadIdx.x;
    const int w = tid >> 6, L = tid & 63, quad = L >> 4, l15 = L & 15;
    const int nper = gridDim.x >> 3;                       // grid divisible by 8
    const int hh = (blockIdx.x & 7) * nper + (blockIdx.x >> 3);
    const int m0 = (hh / 3) * 64;
    const int Nt = hh % 3;                                 // 0..2
    int mA = m0 + w * 16 + l15;
    int gt = wbase * NTOK + mA;
    int wg = gt / 49, tok = gt - wg * 49;
    int bb = wg >> 6, wrem = wg & 63;
    int rr = tok / 7, cc = tok - rr * 7;
    int xrow = bb * NPIX + ((wrem >> 3) * 7 + rr) * 56 + (wrem & 7) * 7 + cc;
    float mean = mv[xrow], rstd = mv[NTOKALL + xrow];
    const float* xr = x + (size_t)xrow * CDIM;
    bf16x8 a[6];
#pragma unroll
    for (int kk = 0; kk < 6; ++kk) {
        int c0 = kk * 32 + quad * 8;
        float4 xv0 = *(const float4*)&xr[c0], xv1 = *(const float4*)&xr[c0 + 4];
        float4 gv0 = *(const float4*)&g1[c0], gv1 = *(const float4*)&g1[c0 + 4];
        float4 bv0 = *(const float4*)&b1[c0], bv1 = *(const float4*)&b1[c0 + 4];
        bf16x8 av;
        av[0] = (short)f2bf((xv0.x - mean) * rstd * gv0.x + bv0.x);
        av[1] = (short)f2bf((xv0.y - mean) * rstd * gv0.y + bv0.y);
        av[2] = (short)f2bf((xv0.z - mean) * rstd * gv0.z + bv0.z);
        av[3] = (short)f2bf((xv0.w - mean) * rstd * gv0.w + bv0.w);
        av[4] = (short)f2bf((xv1.x - mean) * rstd * gv1.x + bv1.x);
        av[5] = (short)f2bf((xv1.y - mean) * rstd * gv1.y + bv1.y);
        av[6] = (short)f2bf((xv1.z - mean) * rstd * gv1.z + bv1.z);
        av[7] = (short)f2bf((xv1.w - mean) * rstd * gv1.w + bv1.w);
        a[kk] = av;
    }
    f32x4 acc[12];
#pragma unroll
    for (int nf = 0; nf < 12; ++nf) acc[nf] = (f32x4){0.f, 0.f, 0.f, 0.f};
    const bf16x8* B = (const bf16x8*)wsw;
#pragma unroll
    for (int kk = 0; kk < 6; ++kk) {
#pragma unroll
        for (int nf = 0; nf < 12; ++nf) {
            bf16x8 bfr = B[(size_t)((Nt * 12 + nf) * 6 + kk) * 64 + L];
            acc[nf] = __builtin_amdgcn_mfma_f32_16x16x32_bf16(a[kk], bfr, acc[nf], 0, 0, 0);
        }
    }
    float qbv[12];
#pragma unroll
    for (int nf = 0; nf < 12; ++nf) qbv[nf] = qb[Nt * 192 + nf * 16 + l15];
#pragma unroll
    for (int i = 0; i < 4; ++i) {
        int mrow = m0 + w * 16 + quad * 4 + i;
        int wrel = mrow / 49, tokr = mrow - wrel * 49;
        unsigned short* obase = qkv + (size_t)wrel * WSTR + tokr * 32;
#pragma unroll
        for (int nf = 0; nf < 12; ++nf) {
            int n = Nt * 192 + nf * 16 + l15;
            int h = n / 96, rem = n - h * 96;
            int part = rem >> 5, d = rem & 31;
            obase[(size_t)(part * 6 + h) * 1568 + d] = f2bf(acc[nf][i] + qbv[nf]);
        }
    }
}

// ----------------------------------------------- k2: windowed attention (head pair)
__global__ __launch_bounds__(128) void k2_attn(
    unsigned short* __restrict__ qkv, const float* __restrict__ abias)
{
    __shared__ float kv[6272];   // [kv part(2)][h(2)][tok 49][d 32], f32
    const int wrel = blockIdx.x / 3;
    const int pair = blockIdx.x - wrel * 3;
    const int h0 = pair * 2;
    unsigned short* base = qkv + (size_t)wrel * WSTR;
    for (int idx = threadIdx.x; idx < 784; idx += 128) {   // 8 elems each
        int part = idx / 392;
        int rem  = idx - part * 392;
        int h    = rem / 196;
        int off8 = rem - h * 196;
        bf16x8 v = *(const bf16x8*)&base[(size_t)((part + 1) * 6 + h0 + h) * 1568 + off8 * 8];
        float* dst = &kv[((part * 2 + h) * 196 + off8) * 8];
        float4 f0 = {bf2f((unsigned short)v[0]), bf2f((unsigned short)v[1]),
                     bf2f((unsigned short)v[2]), bf2f((unsigned short)v[3])};
        float4 f1 = {bf2f((unsigned short)v[4]), bf2f((unsigned short)v[5]),
                     bf2f((unsigned short)v[6]), bf2f((unsigned short)v[7])};
        *(float4*)&dst[0] = f0;
        *(float4*)&dst[4] = f1;
    }
    __syncthreads();
    const int item = threadIdx.x;
    if (item >= 98) return;
    const int h = item / 49;
    const int row = item - h * 49;
    const int hg = h0 + h;
    unsigned short* qptr = base + (size_t)hg * 1568 + row * 32;
    float4 q4[8];
#pragma unroll
    for (int dq2 = 0; dq2 < 4; ++dq2) {
        bf16x8 v = *(const bf16x8*)&qptr[dq2 * 8];
        q4[dq2 * 2]     = (float4){bf2f((unsigned short)v[0]), bf2f((unsigned short)v[1]),
                                   bf2f((unsigned short)v[2]), bf2f((unsigned short)v[3])};
        q4[dq2 * 2 + 1] = (float4){bf2f((unsigned short)v[4]), bf2f((unsigned short)v[5]),
                                   bf2f((unsigned short)v[6]), bf2f((unsigned short)v[7])};
    }
    const int rr = row / 7, rc = row - rr * 7;
    const float scale = 0.17677669529663687f;   // 32^-0.5
    const float* kbase = &kv[(h * 49) * 32];
    const float* vbase = &kv[(98 + h * 49) * 32];
    float s[49];
    for (int j = 0; j < 49; ++j) {
        const float* kr = kbase + j * 32;
        float4 a = {0, 0, 0, 0};
#pragma unroll
        for (int dq = 0; dq < 8; ++dq) {
            float4 k4 = *(const float4*)&kr[dq * 4];
            a.x += q4[dq].x * k4.x; a.y += q4[dq].y * k4.y;
            a.z += q4[dq].z * k4.z; a.w += q4[dq].w * k4.w;
        }
        int jr = j / 7, jc = j - jr * 7;
        int dy = rr > jr ? rr - jr : jr - rr;
        int dx = rc > jc ? rc - jc : jc - rc;
        s[j] = (a.x + a.y + a.z + a.w) * scale + abias[hg * 49 + dy * 7 + dx];
    }
    float mx = s[0];
    for (int j = 1; j < 49; ++j) mx = fmaxf(mx, s[j]);
    float sum = 0.0f;
    for (int j = 0; j < 49; ++j) { s[j] = __expf(s[j] - mx); sum += s[j]; }
    float rinv = 1.0f / sum;
    float4 o[8] = {};
    for (int j = 0; j < 49; ++j) {
        float p = s[j];
        const float* vr = vbase + j * 32;
#pragma unroll
        for (int dq = 0; dq < 8; ++dq) {
            float4 v4 = *(const float4*)&vr[dq * 4];
            o[dq].x += p * v4.x; o[dq].y += p * v4.y;
            o[dq].z += p * v4.z; o[dq].w += p * v4.w;
        }
    }
#pragma unroll
    for (int dq = 0; dq < 8; ++dq) {
        uint2 pk;
        pk.x = (unsigned)f2bf(o[dq].x * rinv) | ((unsigned)f2bf(o[dq].y * rinv) << 16);
        pk.y = (unsigned)f2bf(o[dq].z * rinv) | ((unsigned)f2bf(o[dq].w * rinv) << 16);
        *(uint2*)&qptr[dq * 4] = pk;       // overwrite q slot (own row only)
    }
}

// --------------------------- k3: proj GEMM (MFMA) + bias + residual + window reverse
// Same 1D grid + XCD swizzle as k1 (Nt-siblings share the qkv A-fragment reads).
__global__ __launch_bounds__(256) void k3_proj_mfma(
    const unsigned short* __restrict__ qkv, const float* __restrict__ x,
    const unsigned short* __restrict__ wsw, const float* __restrict__ pb,
    float* __restrict__ x1, int wbase)
{
    const int tid = threadIdx.x;
    const int w = tid >> 6, L = tid & 63, quad = L >> 4, l15 = L & 15;
    const int nper = gridDim.x >> 3;
    const int hh = (blockIdx.x & 7) * nper + (blockIdx.x >> 3);
    const int m0 = (hh / 3) * 64;
    const int Nt = hh % 3;                     // 0..2, 64 cols each
    int mA = m0 + w * 16 + l15;
    int wrelA = mA / 49, tokA = mA - wrelA * 49;
    const unsigned short* ar = qkv + (size_t)wrelA * WSTR + tokA * 32 + quad * 8;
    bf16x8 a[6];
#pragma unroll
    for (int kk = 0; kk < 6; ++kk)             // head = kk
        a[kk] = *(const bf16x8*)&ar[(size_t)kk * 1568];
    f32x4 acc[4];
#pragma unroll
    for (int nf = 0; nf < 4; ++nf) acc[nf] = (f32x4){0.f, 0.f, 0.f, 0.f};
    const bf16x8* B = (const bf16x8*)wsw;
#pragma unroll
    for (int kk = 0; kk < 6; ++kk) {
#pragma unroll
        for (int nf = 0; nf < 4; ++nf) {
            bf16x8 bfr = B[(size_t)((Nt * 4 + nf) * 6 + kk) * 64 + L];
            acc[nf] = __builtin_amdgcn_mfma_f32_16x16x32_bf16(a[kk], bfr, acc[nf], 0, 0, 0);
        }
    }
    float pbv[4];
#pragma unroll
    for (int nf = 0; nf < 4; ++nf) pbv[nf] = pb[Nt * 64 + nf * 16 + l15];
#pragma unroll
    for (int i = 0; i < 4; ++i) {
        int mrow = m0 + w * 16 + quad * 4 + i;
        int wrel = mrow / 49, tokr = mrow - wrel * 49;
        int wg = wbase + wrel;
        int bb = wg >> 6, wrem = wg & 63;
        int r = tokr / 7, c = tokr - r * 7;
        size_t xoff = ((size_t)(bb * NPIX + ((wrem >> 3) * 7 + r) * 56 + (wrem & 7) * 7 + c)) * CDIM;
#pragma unroll
        for (int nf = 0; nf < 4; ++nf) {
            int col = Nt * 64 + nf * 16 + l15;
            x1[xoff + col] = acc[nf][i] + pbv[nf] + x[xoff + col];
        }
    }
}

// ---------------------- k4: depthwise conv3x3 + BN + LN2 stats (1 wave per token)
__global__ __launch_bounds__(256) void k4_convln(
    const float* __restrict__ x1, const float* __restrict__ cwT,
    const float* __restrict__ bnsc, const float* __restrict__ bnbi,
    float* __restrict__ x2, float* __restrict__ mv)
{
    const int w = threadIdx.x >> 6, lane = threadIdx.x & 63;
    const int bid = blockIdx.x;
    const int sbid = (bid & 7) * 3136 + (bid >> 3);   // bijective: 25088 = 8*3136
    const int t = sbid * 4 + w;
    const int b = t / NPIX, l = t - b * NPIX;
    const int yy = l / 56, xx = l - yy * 56;
    const bool act = lane < 48;
    const int c0 = lane * 4;
    float4 o = {0, 0, 0, 0};
    if (act) {
        const float* xb = x1 + (size_t)b * NPIX * CDIM;
        float4 acc = {0, 0, 0, 0};
#pragma unroll
        for (int dy = -1; dy <= 1; ++dy) {
            int y2 = yy + dy;
            if ((unsigned)y2 >= 56u) continue;
#pragma unroll
            for (int dx = -1; dx <= 1; ++dx) {
                int x2c = xx + dx;
                if ((unsigned)x2c >= 56u) continue;
                float4 v = *(const float4*)&xb[(size_t)(y2 * 56 + x2c) * CDIM + c0];
                int tap = (dy + 1) * 3 + (dx + 1);
                float4 wt = *(const float4*)&cwT[tap * CDIM + c0];
                acc.x += v.x * wt.x;
                acc.y += v.y * wt.y;
                acc.z += v.z * wt.z;
                acc.w += v.w * wt.w;
            }
        }
        float4 sc = *(const float4*)&bnsc[c0];
        float4 bi = *(const float4*)&bnbi[c0];
        o.x = acc.x * sc.x + bi.x;
        o.y = acc.y * sc.y + bi.y;
        o.z = acc.z * sc.z + bi.z;
        o.w = acc.w * sc.w + bi.w;
        *(float4*)&x2[(size_t)t * CDIM + c0] = o;
    }
    // LN2 stats (two-pass, butterfly gives sum to all lanes)
    float s = o.x + o.y + o.z + o.w;
    for (int off = 32; off; off >>= 1) s += __shfl_xor(s, off);
    float m = s * (1.0f / 192.0f);
    float d0 = o.x - m, d1 = o.y - m, d2 = o.z - m, d3 = o.w - m;
    float v2 = act ? (d0*d0 + d1*d1 + d2*d2 + d3*d3) : 0.0f;
    for (int off = 32; off; off >>= 1) v2 += __shfl_xor(v2, off);
    if (lane == 0) {
        mv[t] = m;
        mv[NTOKALL + t] = 1.0f / sqrtf(v2 * (1.0f / 192.0f) + LN_EPS);
    }
}

// --------------- k5: LN2 + FC1 + GELU + FC2 + residual (MFMA, LDS-staged A-frags)
// R3 structure (40KB LDS, 6 hidden chunks, nf-split FC2 @1:4 load:MFMA) +
// fast_gelu (R6: k5 176->168us, VALUBusy 57->37%).
__global__ __launch_bounds__(256) void k5_mlp_mfma(
    const float* __restrict__ x2, const float* __restrict__ mv2,
    const float* __restrict__ g2, const float* __restrict__ b2,
    const unsigned short* __restrict__ w1sw, const float* __restrict__ fb1,
    const unsigned short* __restrict__ w2sw, const float* __restrict__ fb2,
    float* __restrict__ out)
{
    __shared__ unsigned short aFrag[24 * 512];   // [mf 4][kk 6][lane 64][8 bf16] = 24KB
    __shared__ unsigned short hsw[16 * 512];     // hidden chunk 64x128, A-frag layout
    const int tid = threadIdx.x;
    const int w = tid >> 6, L = tid & 63, quad = L >> 4, l15 = L & 15;
    const int m0 = blockIdx.x * 64;
    // ---- build LN2(x2) A-fragments into LDS (cooperative, 6 slots/thread)
#pragma unroll
    for (int rsl = 0; rsl < 6; ++rsl) {
        int s = tid + 256 * rsl;                 // 0..1535
        int mf = s / 384, rem = s - mf * 384;
        int kk = rem >> 6, La = rem & 63;
        int row = m0 + mf * 16 + (La & 15);
        int c0 = kk * 32 + (La >> 4) * 8;
        float mm = mv2[row], rs = mv2[NTOKALL + row];
        const float* xr = x2 + (size_t)row * CDIM + c0;
        float4 xv0 = *(const float4*)&xr[0], xv1 = *(const float4*)&xr[4];
        float4 gv0 = *(const float4*)&g2[c0], gv1 = *(const float4*)&g2[c0 + 4];
        float4 bv0 = *(const float4*)&b2[c0], bv1 = *(const float4*)&b2[c0 + 4];
        bf16x8 av;
        av[0] = (short)f2bf((xv0.x - mm) * rs * gv0.x + bv0.x);
        av[1] = (short)f2bf((xv0.y - mm) * rs * gv0.y + bv0.y);
        av[2] = (short)f2bf((xv0.z - mm) * rs * gv0.z + bv0.z);
        av[3] = (short)f2bf((xv0.w - mm) * rs * gv0.w + bv0.w);
        av[4] = (short)f2bf((xv1.x - mm) * rs * gv1.x + bv1.x);
        av[5] = (short)f2bf((xv1.y - mm) * rs * gv1.y + bv1.y);
        av[6] = (short)f2bf((xv1.z - mm) * rs * gv1.z + bv1.z);
        av[7] = (short)f2bf((xv1.w - mm) * rs * gv1.w + bv1.w);
        *(bf16x8*)&aFrag[(size_t)s * 8] = av;
    }
    __syncthreads();

    f32x4 acc2[4][3];    // [mf][nf]  cols = w*48 + nf*16 + l15
#pragma unroll
    for (int mf = 0; mf < 4; ++mf)
#pragma unroll
        for (int nf = 0; nf < 3; ++nf) acc2[mf][nf] = (f32x4){0.f, 0.f, 0.f, 0.f};
    const bf16x8* B1 = (const bf16x8*)w1sw;
    const bf16x8* B2 = (const bf16x8*)w2sw;

    for (int ch = 0; ch < 6; ++ch) {
        // ---- FC1: hidden cols [ch*128 + 32w, +32) for all 64 rows
        f32x4 acc1[4][2];
#pragma unroll
        for (int mf = 0; mf < 4; ++mf)
#pragma unroll
            for (int nf = 0; nf < 2; ++nf) acc1[mf][nf] = (f32x4){0.f, 0.f, 0.f, 0.f};
#pragma unroll
        for (int kk = 0; kk < 6; ++kk) {
            bf16x8 bfr0 = B1[(size_t)((ch * 8 + 2 * w + 0) * 6 + kk) * 64 + L];
            bf16x8 bfr1 = B1[(size_t)((ch * 8 + 2 * w + 1) * 6 + kk) * 64 + L];
#pragma unroll
            for (int mf = 0; mf < 4; ++mf) {
                bf16x8 av = *(const bf16x8*)&aFrag[(size_t)((mf * 6 + kk) * 64 + L) * 8];
                acc1[mf][0] = __builtin_amdgcn_mfma_f32_16x16x32_bf16(av, bfr0, acc1[mf][0], 0, 0, 0);
                acc1[mf][1] = __builtin_amdgcn_mfma_f32_16x16x32_bf16(av, bfr1, acc1[mf][1], 0, 0, 0);
            }
        }
        __syncthreads();   // prior FC2 reads of hsw complete
        // ---- GELU + store hidden in A-frag layout (k-subtile = w)
#pragma unroll
        for (int mf = 0; mf < 4; ++mf) {
#pragma unroll
            for (int nf = 0; nf < 2; ++nf) {
                float bias = fb1[ch * 128 + 32 * w + nf * 16 + l15];
                int hi16 = (((nf * 16 + l15) >> 3) & 3) << 4;
#pragma unroll
                for (int i = 0; i < 4; ++i) {
                    float h = acc1[mf][nf][i] + bias;
                    h = fast_gelu(h);
                    int Ls = (quad * 4 + i) | hi16;
                    hsw[(w * 4 + mf) * 512 + Ls * 8 + (L & 7)] = f2bf(h);
                }
            }
        }
        __syncthreads();
        // ---- FC2 partial (nf-split): acc2[mf][nf] over this chunk's 128 k
#pragma unroll
        for (int kk2 = 0; kk2 < 4; ++kk2) {
            bf16x8 a2[4];
#pragma unroll
            for (int mf = 0; mf < 4; ++mf)
                a2[mf] = *(const bf16x8*)&hsw[(size_t)((kk2 * 4 + mf) * 512) + (size_t)L * 8];
#pragma unroll
            for (int nf = 0; nf < 3; ++nf) {
                bf16x8 bfr = B2[(size_t)((w * 3 + nf) * 24 + ch * 4 + kk2) * 64 + L];
#pragma unroll
                for (int mf = 0; mf < 4; ++mf)
                    acc2[mf][nf] = __builtin_amdgcn_mfma_f32_16x16x32_bf16(a2[mf], bfr, acc2[mf][nf], 0, 0, 0);
            }
        }
    }
    // ---- epilogue: + fc2_b + residual(x2); wave w covers cols [48w, 48w+48)
    float fb2v[3];
#pragma unroll
    for (int nf = 0; nf < 3; ++nf) fb2v[nf] = fb2[w * 48 + nf * 16 + l15];
#pragma unroll
    for (int mf = 0; mf < 4; ++mf) {
#pragma unroll
        for (int i = 0; i < 4; ++i) {
            int row = m0 + mf * 16 + quad * 4 + i;
            const float* xr = x2 + (size_t)row * CDIM;
            float* orow = out + (size_t)row * CDIM;
#pragma unroll
            for (int nf = 0; nf < 3; ++nf) {
                int col = w * 48 + nf * 16 + l15;
                orow[col] = acc2[mf][nf][i] + fb2v[nf] + xr[col];
            }
        }
    }
}

// ------------------------------------------------------------------- launcher
extern "C" void kernel_launch(void* const* d_in, const int* in_sizes, int n_in,
                              void* d_out, int out_size, void* d_ws, size_t ws_size,
                              hipStream_t stream) {
    const float* x     = (const float*)d_in[0];
    const float* g1    = (const float*)d_in[1];
    const float* b1    = (const float*)d_in[2];
    const float* qkvw  = (const float*)d_in[3];
    const float* qkvb  = (const float*)d_in[4];
    const float* abias = (const float*)d_in[5];
    const float* projw = (const float*)d_in[6];
    const float* projb = (const float*)d_in[7];
    const float* convw = (const float*)d_in[8];
    const float* bng   = (const float*)d_in[9];
    const float* bnb   = (const float*)d_in[10];
    const float* bnm   = (const float*)d_in[11];
    const float* bnv   = (const float*)d_in[12];
    const float* g2    = (const float*)d_in[13];
    const float* b2    = (const float*)d_in[14];
    const float* fc1w  = (const float*)d_in[15];
    const float* fc1b  = (const float*)d_in[16];
    const float* fc2w  = (const float*)d_in[17];
    const float* fc2b  = (const float*)d_in[18];
    float* out = (float*)d_out;

    float* wsf = (float*)d_ws;

    // Layout A (single-pass, needs 117.3 MB), all offsets in floats:
    //   [0, 28901376)            qkv bf16, 2048 windows (57.8M shorts); x2b overlays later
    //   [28901376, 29102080)     mv (2 * NTOKALL)
    //   [29102080, 29323264)     swizzled weights: 442368 shorts = 221184 floats
    //   [29323264, 29325376)     cwT (1728) + bnsc (192) + bnbi (192)
    //   (R8 bug: cwT was at 29286400, inside fc2_sw -> NaN. Fixed.)
    // Layout B (fallback, 2 chunks of 1024, ~78.8 MB): legacy offsets.
    const size_t needA = 29325376ull * 4;
    int nchunk, chunkw;
    float *mv, *cwT, *bnsc, *bnbi;
    unsigned short *qkvw_sw;
    if (ws_size >= needA) {
        nchunk = 1;  chunkw = 2048;
        mv      = wsf + 28901376;
        qkvw_sw = (unsigned short*)(wsf + 29102080);
        cwT     = wsf + 29323264;
    } else {
        nchunk = 2;  chunkw = 1024;
        mv      = wsf + 19267584;
        qkvw_sw = (unsigned short*)(wsf + 19468288);
        cwT     = wsf + 19689472;
    }
    unsigned short* qkvws    = (unsigned short*)wsf;
    float*          x2b      = wsf;
    unsigned short* projw_sw = qkvw_sw + 110592;
    unsigned short* fc1_sw   = projw_sw + 36864;
    unsigned short* fc2_sw   = fc1_sw + 147456;
    bnsc = cwT + 1728;
    bnbi = bnsc + 192;

    kw_swz<<<(216 * 64 + 255) / 256, 256, 0, stream>>>(qkvw, qkvw_sw, CDIM, QKVN);
    kw_swz<<<(72  * 64 + 255) / 256, 256, 0, stream>>>(projw, projw_sw, CDIM, CDIM);
    kw_swz<<<(288 * 64 + 255) / 256, 256, 0, stream>>>(fc1w, fc1_sw, CDIM, HIDDEN);
    kw_swz<<<(288 * 64 + 255) / 256, 256, 0, stream>>>(fc2w, fc2_sw, HIDDEN, CDIM);
    k_prep_conv<<<7, 256, 0, stream>>>(convw, bng, bnb, bnm, bnv, cwT, bnsc, bnbi);

    k0_stats<<<NTOKALL / 4, 256, 0, stream>>>(x, mv);
    for (int chunk = 0; chunk < nchunk; ++chunk) {
        int wbase = chunk * chunkw;
        int mt = chunkw * NTOK / 64;          // m-tiles this launch
        k1_qkv_mfma<<<mt * 3, 256, 0, stream>>>(
            x, mv, g1, b1, qkvw_sw, qkvb, qkvws, wbase);
        k2_attn<<<chunkw * 3, 128, 0, stream>>>(qkvws, abias);
        k3_proj_mfma<<<mt * 3, 256, 0, stream>>>(
            qkvws, x, projw_sw, projb, out, wbase);
    }
    k4_convln<<<NTOKALL / 4, 256, 0, stream>>>(out, cwT, bnsc, bnbi, x2b, mv);
    k5_mlp_mfma<<<NTOKALL / 64, 256, 0, stream>>>(
        x2b, mv, g2, b2, fc1_sw, fc1b, fc2_sw, fc2b, out);
}